// Round 12
// baseline (334.829 us; speedup 1.0000x reference)
//
#include <hip/hip_runtime.h>

constexpr int kNR = 40000;
constexpr int kNU = 30000;
constexpr int kNP = 30000;
constexpr int kN  = 100000;          // total nodes
constexpr int kE  = 1600000;         // edges
constexpr int kF  = 128;             // feature/hidden dim
constexpr int kC  = 40;              // classes
constexpr int kAS = 32;              // agg row stride (27 used; 128B rows)
constexpr int kBN = 64;              // nodes per bucket
constexpr int kNB = (kN + kBN - 1) / kBN;   // 1563 buckets
constexpr int kNBp = 1600;           // padded bucket-count stride
constexpr int kCH = 256;             // edge chunks (count/scan granularity)
constexpr int kCE = kE / kCH;        // 6250 edges per chunk (exact)
constexpr int kSG = 4;               // chunks per scatter block (64 blocks, 25000 edges)
constexpr int kColCap = 2048;        // LDS col staging capacity (avg bucket 1024)

typedef __attribute__((ext_vector_type(8))) short bf16x8;   // 4 VGPRs: MFMA A/B frag
typedef __attribute__((ext_vector_type(4))) float f32x4;    // MFMA C/D frag

// ---------- bf16 helpers (storage-only; math in fp32) ----------
__device__ __forceinline__ float bf_to_f(unsigned short h) {
    union { unsigned int i; float f; } u; u.i = ((unsigned int)h) << 16; return u.f;
}
__device__ __forceinline__ unsigned short f_to_bf(float f) {
    union { unsigned int i; float f; } u; u.f = f;
    unsigned int r = u.i + 0x7FFFu + ((u.i >> 16) & 1u);   // round-nearest-even
    return (unsigned short)(r >> 16);
}
__device__ __forceinline__ float2 bf2_to_f2(unsigned int p) {
    union { unsigned int i; float f; } lo, hi;
    lo.i = (p & 0xFFFFu) << 16;
    hi.i = p & 0xFFFF0000u;
    return make_float2(lo.f, hi.f);
}
__device__ __forceinline__ unsigned int pack_bf2(float a, float b) {
    return (unsigned int)f_to_bf(a) | ((unsigned int)f_to_bf(b) << 16);
}
__device__ __forceinline__ float ldf(const void* p, int i, int isbf) {
    return isbf ? bf_to_f(((const unsigned short*)p)[i]) : ((const float*)p)[i];
}
__device__ __forceinline__ int lde(const int* p, int i, int is64) {
    return is64 ? p[2 * i] : p[i];
}

// ---------- sniff dtypes -> flags[0]=isbf, flags[1]=is64 ----------
__global__ void gcn_sniff(const unsigned int* __restrict__ w1w,
                          const int* __restrict__ eiw, int* __restrict__ flags) {
    if (blockIdx.x != 0 || threadIdx.x != 0) return;
    int plaus = 0;
    for (int k = 0; k < 64; k++) {
        unsigned int ax = w1w[k] & 0x7FFFu;
        plaus += (ax == 0u) || (ax > 0x2000u && ax < 0x4000u);
    }
    flags[0] = (plaus >= 48) ? 1 : 0;
    int nz = 0;
    for (int k = 0; k < 64; k++) nz |= eiw[2 * k + 1];
    flags[1] = (nz == 0) ? 1 : 0;
}

// ---------- fused weights, TRANSPOSED bf16: fwT[feat(128)][slot(32)] ----------
__global__ void gcn_fuse(const void* __restrict__ Wr, const void* __restrict__ br,
                         const void* __restrict__ Wu, const void* __restrict__ bu,
                         const void* __restrict__ Wp, const void* __restrict__ bp,
                         const void* __restrict__ W1, unsigned short* __restrict__ fwT,
                         const int* __restrict__ flags) {
    __shared__ float sw[21 * kF];
    int isbf = flags[0];
    int t = threadIdx.x;             // 128 threads
    for (int i = t; i < 21 * kF; i += 128) {
        int r = i >> 7, c = i & 127;
        float v;
        if (r < 5)        v = ldf(Wr, r * kF + c, isbf);
        else if (r < 12)  v = ldf(Wu, (r - 5) * kF + c, isbf);
        else if (r < 18)  v = ldf(Wp, (r - 12) * kF + c, isbf);
        else if (r == 18) v = ldf(br, c, isbf);
        else if (r == 19) v = ldf(bu, c, isbf);
        else              v = ldf(bp, c, isbf);
        sw[i] = v;
    }
    __syncthreads();
    int j = t;
    float acc[21];
    #pragma unroll
    for (int r = 0; r < 21; r++) acc[r] = 0.f;
    for (int k = 0; k < kF; k++) {
        float w1 = ldf(W1, k * kF + j, isbf);
        #pragma unroll
        for (int r = 0; r < 21; r++) acc[r] += sw[r * kF + k] * w1;
    }
    unsigned short row[32];
    #pragma unroll
    for (int s = 0; s < 32; s++) row[s] = 0;
    #pragma unroll
    for (int i = 0; i < 5; i++) row[0  + i] = f_to_bf(acc[i]);
    #pragma unroll
    for (int i = 0; i < 7; i++) row[8  + i] = f_to_bf(acc[5 + i]);
    #pragma unroll
    for (int i = 0; i < 6; i++) row[16 + i] = f_to_bf(acc[12 + i]);
    row[24] = f_to_bf(acc[18]);  row[25] = f_to_bf(acc[19]);  row[26] = f_to_bf(acc[20]);
    #pragma unroll
    for (int s = 0; s < 32; s++) fwT[j * 32 + s] = row[s];
}

// ---------- pack raw features: xpack[n] = uint4 of 8 bf16 (zero-padded) ----------
__global__ void __launch_bounds__(256) gcn_pack(const void* __restrict__ xr,
                                                const void* __restrict__ xu,
                                                const void* __restrict__ xp,
                                                uint4* __restrict__ xpack,
                                                const int* __restrict__ flags) {
    int isbf = flags[0];
    int n = blockIdx.x * 256 + threadIdx.x;
    if (n >= kN) return;
    const void* base; int roff, d;
    if (n < kNR)            { base = xr; roff = n * 5;               d = 5; }
    else if (n < kNR + kNU) { base = xu; roff = (n - kNR) * 7;       d = 7; }
    else                    { base = xp; roff = (n - kNR - kNU) * 6; d = 6; }
    float f[8];
    #pragma unroll
    for (int i = 0; i < 8; i++) f[i] = (i < d) ? ldf(base, roff + i, isbf) : 0.f;
    uint4 u;
    u.x = pack_bf2(f[0], f[1]);  u.y = pack_bf2(f[2], f[3]);
    u.z = pack_bf2(f[4], f[5]);  u.w = pack_bf2(f[6], f[7]);
    xpack[n] = u;
}

// ---------- multisplit pass 1: per-chunk bucket counts -> cmat[chunk][kNBp] ----------
__global__ void __launch_bounds__(512) gcn_count(const int* __restrict__ ei,
                                                 int* __restrict__ cmat,
                                                 const int* __restrict__ flags) {
    __shared__ int cl[kNBp];
    int is64 = flags[1];
    int blk = blockIdx.x, t = threadIdx.x;
    for (int i = t; i < kNBp; i += 512) cl[i] = 0;
    __syncthreads();
    int e0 = blk * kCE, e1 = e0 + kCE;
    for (int eb = e0 + t; eb < e1; eb += 2048) {        // 4-wide MLP batch
        unsigned int d[4]; int ok[4];
        #pragma unroll
        for (int j = 0; j < 4; j++) {
            int e = eb + j * 512;
            ok[j] = (e < e1);
            d[j] = ok[j] ? (unsigned int)lde(ei, kE + e, is64) : 0u;
        }
        #pragma unroll
        for (int j = 0; j < 4; j++)
            if (ok[j] && d[j] < (unsigned int)kN) atomicAdd(&cl[d[j] >> 6], 1);
    }
    __syncthreads();
    for (int i = t; i < kNBp; i += 512) cmat[blk * kNBp + i] = cl[i];   // coalesced
}

// ---------- pass 2a: per-bucket scan over chunks -> reloff[b][chunk], btot[b] ----------
__global__ void gcn_scanB1(const int* __restrict__ cmat, int* __restrict__ reloff,
                           int* __restrict__ btot) {
    __shared__ int lds[256];
    int b = blockIdx.x, t = threadIdx.x;
    int v = cmat[t * kNBp + b];
    int incl = v; lds[t] = incl; __syncthreads();
    for (int o = 1; o < 256; o <<= 1) {
        int y = (t >= o) ? lds[t - o] : 0;
        __syncthreads();
        incl += y; lds[t] = incl;
        __syncthreads();
    }
    reloff[b * 256 + t] = incl - v;
    if (t == 255) btot[b] = incl;
}

// ---------- pass 2b: scan 1563 bucket totals -> bbase[0..kNB] ----------
__global__ void gcn_scanB2(const int* __restrict__ btot, int* __restrict__ bbase) {
    __shared__ int lds[512];
    int t = threadIdx.x;
    int v[4]; int s = 0;
    #pragma unroll
    for (int j = 0; j < 4; j++) {
        int i = 4 * t + j;
        v[j] = (i < kNB) ? btot[i] : 0;
        s += v[j];
    }
    int incl = s; lds[t] = incl; __syncthreads();
    for (int o = 1; o < 512; o <<= 1) {
        int y = (t >= o) ? lds[t - o] : 0;
        __syncthreads();
        incl += y; lds[t] = incl;
        __syncthreads();
    }
    int excl = incl - s;
    #pragma unroll
    for (int j = 0; j < 4; j++) {
        int i = 4 * t + j;
        if (i < kNB) { bbase[i] = excl; excl += v[j]; }
    }
    if (t == 511) bbase[kNB] = incl;
}

// ---------- pass 3: scatter pairs. 64 blocks x 4 consecutive chunks each ----------
// Cursors init once at reloff[b][4*blk]; valid across the block's whole 25000-edge
// range (prefix additivity; downstream needs bucket-grouping only). Runs per
// (block,bucket) ~16 edges = 64B written by ONE block -> full-line evictions.
__global__ void __launch_bounds__(512) gcn_scatter(const int* __restrict__ ei,
                                                   const int* __restrict__ bbase,
                                                   const int* __restrict__ reloff,
                                                   unsigned int* __restrict__ pairs,
                                                   const int* __restrict__ flags) {
    __shared__ int cur[kNB];
    int is64 = flags[1];
    int blk = blockIdx.x, t = threadIdx.x;
    int c0 = blk * kSG;
    for (int i = t; i < kNB; i += 512) cur[i] = bbase[i] + reloff[i * 256 + c0];
    __syncthreads();
    int e0 = c0 * kCE, e1 = e0 + kSG * kCE;
    for (int eb = e0 + t; eb < e1; eb += 2048) {        // 4-wide MLP batch
        unsigned int d[4], s[4]; int ok[4];
        #pragma unroll
        for (int j = 0; j < 4; j++) {
            int e = eb + j * 512;
            ok[j] = (e < e1);
            d[j] = ok[j] ? (unsigned int)lde(ei, kE + e, is64) : 0xFFFFFFFFu;
        }
        #pragma unroll
        for (int j = 0; j < 4; j++) {
            int e = eb + j * 512;
            s[j] = ok[j] ? (unsigned int)lde(ei, e, is64) : 0u;
        }
        #pragma unroll
        for (int j = 0; j < 4; j++) {
            if (d[j] < (unsigned int)kN) {
                unsigned int sv = (s[j] < (unsigned int)kN) ? s[j] : 0u;
                int p = atomicAdd(&cur[d[j] >> 6], 1);
                pairs[p] = (sv << 6) | (d[j] & 63u);
            }
        }
    }
}

// ---------- bucket kernel: node-CSR build (rp,col) + layer-1 LDS fp32 aggregation ----------
__global__ void __launch_bounds__(256) GCN_2190433321521_kernel(
        const unsigned int* __restrict__ pairs,
        const int* __restrict__ bbase,
        const uint4* __restrict__ xpack,
        int* __restrict__ rp,
        int* __restrict__ col,
        float* __restrict__ agg) {
    __shared__ float agg_l[kBN][29];    // stride 29 breaks mod-32 bank aliasing
    __shared__ int   cnt_l[kBN];
    __shared__ int   scan_l[kBN];
    __shared__ int   col_l[kColCap];    // 8 KB staging
    int b = blockIdx.x;
    int base = b * kBN;
    int nn = min(kBN, kN - base);
    int tid = threadIdx.x;
    float* aflat = (float*)agg_l;
    for (int i = tid; i < kBN * 29; i += 256) aflat[i] = 0.f;
    if (tid < kBN) cnt_l[tid] = 0;
    __syncthreads();
    int p0 = bbase[b], p1 = bbase[b + 1];
    int m = p1 - p0;

    // pass 1: per-node histogram (4-wide batch for MLP)
    for (int ib = p0 + tid; ib < p1; ib += 1024) {
        unsigned int w[4]; int ok[4];
        #pragma unroll
        for (int j = 0; j < 4; j++) {
            int i = ib + j * 256;
            ok[j] = (i < p1);
            w[j] = ok[j] ? pairs[i] : 0u;
        }
        #pragma unroll
        for (int j = 0; j < 4; j++)
            if (ok[j]) atomicAdd(&cnt_l[w[j] & 63u], 1);
    }
    __syncthreads();
    // LDS scan over 64 node-counts
    int v = (tid < kBN) ? cnt_l[tid] : 0;
    int incl = v;
    if (tid < kBN) scan_l[tid] = incl;
    __syncthreads();
    for (int o = 1; o < kBN; o <<= 1) {
        int y = (tid < kBN && tid >= o) ? scan_l[tid - o] : 0;
        __syncthreads();
        if (tid < kBN) { incl += y; scan_l[tid] = incl; }
        __syncthreads();
    }
    if (tid < kBN) {
        int cursor = p0 + incl - v;
        cnt_l[tid] = cursor;
        if (tid < nn) rp[base + tid] = cursor;
    }
    if (b == kNB - 1 && tid == 0) rp[kN] = p1;
    __syncthreads();

    // pass 2: col build + agg accumulate (4-wide: pairs loads, then xpack loads, then process)
    bool fits = (m <= kColCap);
    for (int ib = p0 + tid; ib < p1; ib += 1024) {
        unsigned int w[4]; uint4 u[4]; int ok[4];
        #pragma unroll
        for (int j = 0; j < 4; j++) {
            int i = ib + j * 256;
            ok[j] = (i < p1);
            w[j] = ok[j] ? pairs[i] : 0u;
        }
        #pragma unroll
        for (int j = 0; j < 4; j++)
            if (ok[j]) u[j] = xpack[w[j] >> 6];
        #pragma unroll
        for (int j = 0; j < 4; j++) {
            if (!ok[j]) continue;
            unsigned int s = w[j] >> 6;
            int dloc = (int)(w[j] & 63u);
            int pos = atomicAdd(&cnt_l[dloc], 1);
            if (fits) col_l[pos - p0] = (int)s;
            else      col[pos] = (int)s;
            int sb = (s < (unsigned int)kNR) ? 0 : ((s < (unsigned int)(kNR + kNU)) ? 8 : 16);
            float2 q0 = bf2_to_f2(u[j].x), q1 = bf2_to_f2(u[j].y);
            float2 q2 = bf2_to_f2(u[j].z), q3 = bf2_to_f2(u[j].w);
            float* a = &agg_l[dloc][sb];
            atomicAdd(&a[0], q0.x); atomicAdd(&a[1], q0.y);
            atomicAdd(&a[2], q1.x); atomicAdd(&a[3], q1.y);
            atomicAdd(&a[4], q2.x); atomicAdd(&a[5], q2.y);
            atomicAdd(&a[6], q3.x); atomicAdd(&a[7], q3.y);
            atomicAdd(&agg_l[dloc][24 + (sb >> 3)], 1.f);
        }
    }
    __syncthreads();
    if (fits) {
        for (int i = tid; i < m; i += 256) col[p0 + i] = col_l[i];   // coalesced
    }
    for (int i = tid; i < nn * 32; i += 256) {
        int n = i >> 5, sl = i & 31;
        agg[(size_t)(base + n) * kAS + sl] = (sl < 27) ? agg_l[n][sl] : 0.f;
    }
}

// ---------- dense via MFMA: one wave per 16 nodes (verified R7) ----------
__global__ void __launch_bounds__(256) gcn_dense(const float* __restrict__ agg,
                                                 const unsigned short* __restrict__ fwT,
                                                 const void* __restrict__ W2,
                                                 unsigned short* __restrict__ hw,
                                                 const int* __restrict__ flags) {
    __shared__ __align__(16) unsigned short sfwT[kF][40];
    __shared__ __align__(16) unsigned short sw2T[48][136];
    __shared__ __align__(16) unsigned short hbuf[4][16][136];
    int isbf = flags[0];
    int tid = threadIdx.x;
    for (int i = tid; i < kF * 32; i += 256) sfwT[i >> 5][i & 31] = fwT[i];
    for (int i = tid; i < 48 * kF; i += 256) {
        int c = i >> 7, k = i & 127;
        sw2T[c][k] = (c < kC) ? f_to_bf(ldf(W2, k * kC + c, isbf)) : (unsigned short)0;
    }
    __syncthreads();
    int wid = tid >> 6, lane = tid & 63;
    int T = blockIdx.x * 4 + wid;
    if (T >= kN / 16) return;
    int n0 = T * 16;
    int m = lane & 15, q = lane >> 4;

    const float* ar = agg + (size_t)(n0 + m) * kAS + q * 8;
    bf16x8 a1;
    #pragma unroll
    for (int i = 0; i < 8; i++) a1[i] = (short)f_to_bf(ar[i]);

    f32x4 c1[8];
    #pragma unroll
    for (int t = 0; t < 8; t++) {
        bf16x8 bfr = *(const bf16x8*)&sfwT[16 * t + m][q * 8];
        f32x4 z = {0.f, 0.f, 0.f, 0.f};
        c1[t] = __builtin_amdgcn_mfma_f32_16x16x32_bf16(a1, bfr, z, 0, 0, 0);
    }
    #pragma unroll
    for (int t = 0; t < 8; t++) {
        #pragma unroll
        for (int r = 0; r < 4; r++)
            hbuf[wid][q * 4 + r][16 * t + m] = f_to_bf(fmaxf(c1[t][r], 0.f));
    }
    f32x4 c2[3];
    #pragma unroll
    for (int t = 0; t < 3; t++) { c2[t].x = 0.f; c2[t].y = 0.f; c2[t].z = 0.f; c2[t].w = 0.f; }
    #pragma unroll
    for (int s = 0; s < 4; s++) {
        bf16x8 a2 = *(const bf16x8*)&hbuf[wid][m][s * 32 + q * 8];
        #pragma unroll
        for (int t = 0; t < 3; t++) {
            bf16x8 b2 = *(const bf16x8*)&sw2T[16 * t + m][s * 32 + q * 8];
            c2[t] = __builtin_amdgcn_mfma_f32_16x16x32_bf16(a2, b2, c2[t], 0, 0, 0);
        }
    }
    #pragma unroll
    for (int t = 0; t < 3; t++) {
        int cls = 16 * t + m;
        if (cls < kC) {
            #pragma unroll
            for (int r = 0; r < 4; r++)
                hw[(size_t)(n0 + q * 4 + r) * kC + cls] = f_to_bf(c2[t][r]);
        }
    }
}

// ---------- layer-2 gather: wave-per-node, 3 groups x 20 class-lanes, 4 rows in flight ----------
__global__ void __launch_bounds__(256) gcn_gather2(const unsigned int* __restrict__ hw32,
                                                   const int* __restrict__ rp,
                                                   const int* __restrict__ col,
                                                   unsigned int* __restrict__ out,
                                                   const int* __restrict__ flags) {
    int isbf = flags[0];
    int w = (blockIdx.x * 256 + threadIdx.x) >> 6;
    if (w >= kN) return;
    int lane = threadIdx.x & 63;
    int grp = lane / 20;
    int c2  = lane % 20;
    int beg = rp[w], end = rp[w + 1];
    float ax = 0.f, ay = 0.f;
    if (grp < 3) {
        int e = beg + grp;
        for (; e + 9 < end; e += 12) {           // 4 rows in flight per group
            int s0 = col[e], s1 = col[e + 3], s2 = col[e + 6], s3 = col[e + 9];
            float2 f0 = bf2_to_f2(hw32[s0 * 20 + c2]);
            float2 f1 = bf2_to_f2(hw32[s1 * 20 + c2]);
            float2 f2 = bf2_to_f2(hw32[s2 * 20 + c2]);
            float2 f3 = bf2_to_f2(hw32[s3 * 20 + c2]);
            ax += (f0.x + f1.x) + (f2.x + f3.x);
            ay += (f0.y + f1.y) + (f2.y + f3.y);
        }
        for (; e < end; e += 3) {
            float2 f = bf2_to_f2(hw32[col[e] * 20 + c2]);
            ax += f.x; ay += f.y;
        }
    }
    ax += __shfl(ax, lane + 20, 64) + __shfl(ax, lane + 40, 64);
    ay += __shfl(ay, lane + 20, 64) + __shfl(ay, lane + 40, 64);
    if (lane < 20) {
        if (isbf) {
            out[w * 20 + lane] = pack_bf2(ax, ay);
        } else {
            float* of = (float*)out;
            of[w * 40 + 2*lane]     = ax;
            of[w * 40 + 2*lane + 1] = ay;
        }
    }
}

extern "C" void kernel_launch(void* const* d_in, const int* in_sizes, int n_in,
                              void* d_out, int out_size, void* d_ws, size_t ws_size,
                              hipStream_t stream) {
    const void* xr = d_in[0];
    const void* xu = d_in[1];
    const void* xp = d_in[2];
    const int*  ei = (const int*)d_in[3];
    const void* Wr = d_in[4];
    const void* br = d_in[5];
    const void* Wu = d_in[6];
    const void* bu = d_in[7];
    const void* Wp = d_in[8];
    const void* bp = d_in[9];
    const void* W1 = d_in[10];
    const void* W2 = d_in[11];
    (void)in_sizes; (void)n_in; (void)out_size; (void)ws_size;

    char* ws = (char*)d_ws;
    size_t off = 0;
    auto alloc = [&](size_t bytes) -> void* {
        void* p = (void*)(ws + off);
        off = (off + bytes + 255) & ~(size_t)255;
        return p;
    };
    int*            flags  = (int*)           alloc(256);
    int*            cmat   = (int*)           alloc((size_t)kCH * kNBp * 4);  // 1.6 MB
    int*            reloff = (int*)           alloc((size_t)kNB * 256 * 4);   // 1.6 MB
    int*            btot   = (int*)           alloc((size_t)kNB * 4);
    int*            bbase  = (int*)           alloc((size_t)(kNB + 1) * 4);
    int*            rp     = (int*)           alloc((size_t)(kN + 1) * 4);
    unsigned short* fwT    = (unsigned short*)alloc(kF * 32 * 2);             // 8 KB
    uint4*          xpack  = (uint4*)         alloc((size_t)kN * 16);         // 1.6 MB
    unsigned int*   pairs  = (unsigned int*)  alloc((size_t)kE * 4);          // 6.4 MB
    int*            col    = (int*)           alloc((size_t)kE * 4);          // 6.4 MB
    unsigned short* hwb    = (unsigned short*)alloc((size_t)kN * kC * 2);     // 8 MB
    float*          agg    = (float*)         alloc((size_t)kN * kAS * 4);    // 12.8 MB

    gcn_sniff<<<1, 64, 0, stream>>>((const unsigned int*)W1, ei, flags);
    gcn_fuse<<<1, 128, 0, stream>>>(Wr, br, Wu, bu, Wp, bp, W1, fwT, flags);
    gcn_pack<<<(kN + 255) / 256, 256, 0, stream>>>(xr, xu, xp, xpack, flags);
    gcn_count<<<kCH, 512, 0, stream>>>(ei, cmat, flags);
    gcn_scanB1<<<kNB, 256, 0, stream>>>(cmat, reloff, btot);
    gcn_scanB2<<<1, 512, 0, stream>>>(btot, bbase);
    gcn_scatter<<<kCH / kSG, 512, 0, stream>>>(ei, bbase, reloff, pairs, flags);
    GCN_2190433321521_kernel<<<kNB, 256, 0, stream>>>(pairs, bbase, xpack, rp, col, agg);
    gcn_dense<<<(kN / 16 + 3) / 4, 256, 0, stream>>>(agg, fwT, W2, hwb, flags);
    gcn_gather2<<<(kN * 64 + 255) / 256, 256, 0, stream>>>((const unsigned int*)hwb, rp, col,
                                                           (unsigned int*)d_out, flags);
}

// Round 13
// 326.347 us; speedup vs baseline: 1.0260x; 1.0260x over previous
//
#include <hip/hip_runtime.h>

constexpr int kNR = 40000;
constexpr int kNU = 30000;
constexpr int kNP = 30000;
constexpr int kN  = 100000;          // total nodes
constexpr int kE  = 1600000;         // edges
constexpr int kF  = 128;             // feature/hidden dim
constexpr int kC  = 40;              // classes
constexpr int kBN = 64;              // nodes per bucket
constexpr int kNB = (kN + kBN - 1) / kBN;   // 1563 buckets
constexpr int kNBp = 1600;           // padded bucket-count stride
constexpr int kCH = 256;             // edge chunks (count/scan granularity)
constexpr int kCE = kE / kCH;        // 6250 edges per chunk
constexpr int kSG = 4;               // chunks per scatter block (64 blocks)
constexpr int kStash = 2048;         // LDS pair-stash capacity (avg bucket 1024)

typedef __attribute__((ext_vector_type(8))) short bf16x8;   // MFMA A/B frag
typedef __attribute__((ext_vector_type(4))) float f32x4;    // MFMA C/D frag

// ---------- bf16 helpers ----------
__device__ __forceinline__ float bf_to_f(unsigned short h) {
    union { unsigned int i; float f; } u; u.i = ((unsigned int)h) << 16; return u.f;
}
__device__ __forceinline__ unsigned short f_to_bf(float f) {
    union { unsigned int i; float f; } u; u.f = f;
    unsigned int r = u.i + 0x7FFFu + ((u.i >> 16) & 1u);   // RNE
    return (unsigned short)(r >> 16);
}
__device__ __forceinline__ float2 bf2_to_f2(unsigned int p) {
    union { unsigned int i; float f; } lo, hi;
    lo.i = (p & 0xFFFFu) << 16;
    hi.i = p & 0xFFFF0000u;
    return make_float2(lo.f, hi.f);
}
__device__ __forceinline__ unsigned int pack_bf2(float a, float b) {
    return (unsigned int)f_to_bf(a) | ((unsigned int)f_to_bf(b) << 16);
}
__device__ __forceinline__ float ldf(const void* p, int i, int isbf) {
    return isbf ? bf_to_f(((const unsigned short*)p)[i]) : ((const float*)p)[i];
}
__device__ __forceinline__ int lde(const int* p, int i, int is64) {
    return is64 ? p[2 * i] : p[i];
}

// ---------- sniff dtypes -> flags[0]=isbf, flags[1]=is64 ----------
__global__ void gcn_sniff(const unsigned int* __restrict__ w1w,
                          const int* __restrict__ eiw, int* __restrict__ flags) {
    if (blockIdx.x != 0 || threadIdx.x != 0) return;
    int plaus = 0;
    for (int k = 0; k < 64; k++) {
        unsigned int ax = w1w[k] & 0x7FFFu;
        plaus += (ax == 0u) || (ax > 0x2000u && ax < 0x4000u);
    }
    flags[0] = (plaus >= 48) ? 1 : 0;
    int nz = 0;
    for (int k = 0; k < 64; k++) nz |= eiw[2 * k + 1];
    flags[1] = (nz == 0) ? 1 : 0;
}

// ---------- setup: blocks 0..390 pack features; block 391 computes fused weights ----------
// fwT[feat(128)][slot(32)] bf16: slots 0-4 Wr@W1 | 8-14 Wu@W1 | 16-21 Wp@W1 | 24-26 biases
__global__ void __launch_bounds__(256) gcn_setup(
        const void* __restrict__ xr, const void* __restrict__ xu, const void* __restrict__ xp,
        const void* __restrict__ Wr, const void* __restrict__ br,
        const void* __restrict__ Wu, const void* __restrict__ bu,
        const void* __restrict__ Wp, const void* __restrict__ bp,
        const void* __restrict__ W1, unsigned short* __restrict__ fwT,
        uint4* __restrict__ xpack, const int* __restrict__ flags) {
    int isbf = flags[0];
    int t = threadIdx.x;
    if (blockIdx.x == 391) {                 // ---- fuse ----
        __shared__ float sw[21 * kF];
        for (int i = t; i < 21 * kF; i += 256) {
            int r = i >> 7, c = i & 127;
            float v;
            if (r < 5)        v = ldf(Wr, r * kF + c, isbf);
            else if (r < 12)  v = ldf(Wu, (r - 5) * kF + c, isbf);
            else if (r < 18)  v = ldf(Wp, (r - 12) * kF + c, isbf);
            else if (r == 18) v = ldf(br, c, isbf);
            else if (r == 19) v = ldf(bu, c, isbf);
            else              v = ldf(bp, c, isbf);
            sw[i] = v;
        }
        __syncthreads();
        if (t < 128) {
            int j = t;
            float acc[21];
            #pragma unroll
            for (int r = 0; r < 21; r++) acc[r] = 0.f;
            for (int k = 0; k < kF; k++) {
                float w1 = ldf(W1, k * kF + j, isbf);
                #pragma unroll
                for (int r = 0; r < 21; r++) acc[r] += sw[r * kF + k] * w1;
            }
            unsigned short row[32];
            #pragma unroll
            for (int s = 0; s < 32; s++) row[s] = 0;
            #pragma unroll
            for (int i = 0; i < 5; i++) row[0  + i] = f_to_bf(acc[i]);
            #pragma unroll
            for (int i = 0; i < 7; i++) row[8  + i] = f_to_bf(acc[5 + i]);
            #pragma unroll
            for (int i = 0; i < 6; i++) row[16 + i] = f_to_bf(acc[12 + i]);
            row[24] = f_to_bf(acc[18]);  row[25] = f_to_bf(acc[19]);  row[26] = f_to_bf(acc[20]);
            #pragma unroll
            for (int s = 0; s < 32; s++) fwT[j * 32 + s] = row[s];
        }
    } else {                                 // ---- pack ----
        int n = blockIdx.x * 256 + t;
        if (n >= kN) return;
        const void* base; int roff, d;
        if (n < kNR)            { base = xr; roff = n * 5;               d = 5; }
        else if (n < kNR + kNU) { base = xu; roff = (n - kNR) * 7;       d = 7; }
        else                    { base = xp; roff = (n - kNR - kNU) * 6; d = 6; }
        float f[8];
        #pragma unroll
        for (int i = 0; i < 8; i++) f[i] = (i < d) ? ldf(base, roff + i, isbf) : 0.f;
        uint4 u;
        u.x = pack_bf2(f[0], f[1]);  u.y = pack_bf2(f[2], f[3]);
        u.z = pack_bf2(f[4], f[5]);  u.w = pack_bf2(f[6], f[7]);
        xpack[n] = u;
    }
}

// ---------- multisplit pass 1: per-chunk bucket counts ----------
__global__ void __launch_bounds__(512) gcn_count(const int* __restrict__ ei,
                                                 int* __restrict__ cmat,
                                                 const int* __restrict__ flags) {
    __shared__ int cl[kNBp];
    int is64 = flags[1];
    int blk = blockIdx.x, t = threadIdx.x;
    for (int i = t; i < kNBp; i += 512) cl[i] = 0;
    __syncthreads();
    int e0 = blk * kCE, e1 = e0 + kCE;
    for (int eb = e0 + t; eb < e1; eb += 2048) {
        unsigned int d[4]; int ok[4];
        #pragma unroll
        for (int j = 0; j < 4; j++) {
            int e = eb + j * 512;
            ok[j] = (e < e1);
            d[j] = ok[j] ? (unsigned int)lde(ei, kE + e, is64) : 0u;
        }
        #pragma unroll
        for (int j = 0; j < 4; j++)
            if (ok[j] && d[j] < (unsigned int)kN) atomicAdd(&cl[d[j] >> 6], 1);
    }
    __syncthreads();
    for (int i = t; i < kNBp; i += 512) cmat[blk * kNBp + i] = cl[i];
}

// ---------- pass 2a: per-bucket scan over chunks ----------
__global__ void gcn_scanB1(const int* __restrict__ cmat, int* __restrict__ reloff,
                           int* __restrict__ btot) {
    __shared__ int lds[256];
    int b = blockIdx.x, t = threadIdx.x;
    int v = cmat[t * kNBp + b];
    int incl = v; lds[t] = incl; __syncthreads();
    for (int o = 1; o < 256; o <<= 1) {
        int y = (t >= o) ? lds[t - o] : 0;
        __syncthreads();
        incl += y; lds[t] = incl;
        __syncthreads();
    }
    reloff[b * 256 + t] = incl - v;
    if (t == 255) btot[b] = incl;
}

// ---------- pass 2b: scan bucket totals -> bbase ----------
__global__ void gcn_scanB2(const int* __restrict__ btot, int* __restrict__ bbase) {
    __shared__ int lds[512];
    int t = threadIdx.x;
    int v[4]; int s = 0;
    #pragma unroll
    for (int j = 0; j < 4; j++) {
        int i = 4 * t + j;
        v[j] = (i < kNB) ? btot[i] : 0;
        s += v[j];
    }
    int incl = s; lds[t] = incl; __syncthreads();
    for (int o = 1; o < 512; o <<= 1) {
        int y = (t >= o) ? lds[t - o] : 0;
        __syncthreads();
        incl += y; lds[t] = incl;
        __syncthreads();
    }
    int excl = incl - s;
    #pragma unroll
    for (int j = 0; j < 4; j++) {
        int i = 4 * t + j;
        if (i < kNB) { bbase[i] = excl; excl += v[j]; }
    }
    if (t == 511) bbase[kNB] = incl;
}

// ---------- pass 3: scatter pairs; 64 blocks x 4 consecutive chunks ----------
__global__ void __launch_bounds__(512) gcn_scatter(const int* __restrict__ ei,
                                                   const int* __restrict__ bbase,
                                                   const int* __restrict__ reloff,
                                                   unsigned int* __restrict__ pairs,
                                                   const int* __restrict__ flags) {
    __shared__ int cur[kNB];
    int is64 = flags[1];
    int blk = blockIdx.x, t = threadIdx.x;
    int c0 = blk * kSG;
    for (int i = t; i < kNB; i += 512) cur[i] = bbase[i] + reloff[i * 256 + c0];
    __syncthreads();
    int e0 = c0 * kCE, e1 = e0 + kSG * kCE;
    for (int eb = e0 + t; eb < e1; eb += 2048) {
        unsigned int d[4], s[4]; int ok[4];
        #pragma unroll
        for (int j = 0; j < 4; j++) {
            int e = eb + j * 512;
            ok[j] = (e < e1);
            d[j] = ok[j] ? (unsigned int)lde(ei, kE + e, is64) : 0xFFFFFFFFu;
        }
        #pragma unroll
        for (int j = 0; j < 4; j++) {
            int e = eb + j * 512;
            s[j] = ok[j] ? (unsigned int)lde(ei, e, is64) : 0u;
        }
        #pragma unroll
        for (int j = 0; j < 4; j++) {
            if (d[j] < (unsigned int)kN) {
                unsigned int sv = (s[j] < (unsigned int)kN) ? s[j] : 0u;
                int p = atomicAdd(&cur[d[j] >> 6], 1);
                pairs[p] = (sv << 6) | (d[j] & 63u);
            }
        }
    }
}

// ---------- MEGA bucket kernel: CSR build + layer-1 agg + fused MFMA dense ----------
// Per 64-node bucket: LDS pair-stash + node hist/scan -> rp,col; fp32 agg in LDS;
// then (no agg round-trip) 4 waves run h=relu(agg@fwT^T), hw=h@W2 via MFMA -> hw.
__global__ void __launch_bounds__(256) GCN_2190433321521_kernel(
        const unsigned int* __restrict__ pairs,
        const int* __restrict__ bbase,
        const uint4* __restrict__ xpack,
        const unsigned short* __restrict__ fwT,
        const void* __restrict__ W2,
        int* __restrict__ rp,
        int* __restrict__ col,
        unsigned short* __restrict__ hw,
        const int* __restrict__ flags) {
    // manual LDS carve; hbuf aliases the pair-stash region (phase-disjoint)
    __shared__ __align__(16) char smem[7424 + 256 + 256 + 8192 + 13056 + 17408];
    float*          agg_l  = (float*)smem;                       // [64][29] fp32, 7424 B
    int*            cnt_l  = (int*)(smem + 7424);                // [64]
    int*            scan_l = (int*)(smem + 7424 + 256);          // [64]
    unsigned short* sfwT   = (unsigned short*)(smem + 7936);     // [128][32] bf16, 8192 B
    unsigned short* sw2T   = (unsigned short*)(smem + 16128);    // [48][136] bf16, 13056 B
    unsigned short* hbuf   = (unsigned short*)(smem + 29184);    // [4][16][136] bf16, 17408 B
    unsigned int*   wst    = (unsigned int*)(smem + 29184);      // pair stash [2048] (aliases hbuf)

    int isbf = flags[0];
    int b = blockIdx.x;
    int base = b * kBN;
    int nn = min(kBN, kN - base);
    int tid = threadIdx.x;

    for (int i = tid; i < kBN * 29; i += 256) agg_l[i] = 0.f;
    if (tid < kBN) cnt_l[tid] = 0;
    for (int i = tid; i < kF * 32; i += 256) sfwT[i] = fwT[i];
    for (int i = tid; i < 48 * kF; i += 256) {
        int c = i >> 7, k = i & 127;
        sw2T[c * 136 + k] = (c < kC) ? f_to_bf(ldf(W2, k * kC + c, isbf)) : (unsigned short)0;
    }
    __syncthreads();
    int p0 = bbase[b], p1 = bbase[b + 1];
    int m = p1 - p0;
    bool fits = (m <= kStash);

    // pass 1: load pairs once -> stash + per-node histogram
    for (int ib = p0 + tid; ib < p1; ib += 1024) {
        unsigned int w[4]; int ok[4];
        #pragma unroll
        for (int j = 0; j < 4; j++) {
            int i = ib + j * 256;
            ok[j] = (i < p1);
            w[j] = ok[j] ? pairs[i] : 0u;
        }
        #pragma unroll
        for (int j = 0; j < 4; j++) {
            int i = ib + j * 256;
            if (ok[j]) {
                if (fits) wst[i - p0] = w[j];
                atomicAdd(&cnt_l[w[j] & 63u], 1);
            }
        }
    }
    __syncthreads();
    // scan 64 node-counts -> cursors + rp
    int v = (tid < kBN) ? cnt_l[tid] : 0;
    int incl = v;
    if (tid < kBN) scan_l[tid] = incl;
    __syncthreads();
    for (int o = 1; o < kBN; o <<= 1) {
        int y = (tid < kBN && tid >= o) ? scan_l[tid - o] : 0;
        __syncthreads();
        if (tid < kBN) { incl += y; scan_l[tid] = incl; }
        __syncthreads();
    }
    if (tid < kBN) {
        int cursor = p0 + incl - v;
        cnt_l[tid] = cursor;
        if (tid < nn) rp[base + tid] = cursor;
    }
    if (b == kNB - 1 && tid == 0) rp[kN] = p1;
    __syncthreads();

    // pass 2: col build (direct write to block-owned 4KB window) + agg accumulate
    for (int ib = p0 + tid; ib < p1; ib += 1024) {
        unsigned int w[4]; uint4 u[4]; int ok[4];
        #pragma unroll
        for (int j = 0; j < 4; j++) {
            int i = ib + j * 256;
            ok[j] = (i < p1);
            w[j] = ok[j] ? (fits ? wst[i - p0] : pairs[i]) : 0u;
        }
        #pragma unroll
        for (int j = 0; j < 4; j++)
            if (ok[j]) u[j] = xpack[w[j] >> 6];
        #pragma unroll
        for (int j = 0; j < 4; j++) {
            if (!ok[j]) continue;
            unsigned int s = w[j] >> 6;
            int dloc = (int)(w[j] & 63u);
            int pos = atomicAdd(&cnt_l[dloc], 1);
            col[pos] = (int)s;
            int sb = (s < (unsigned int)kNR) ? 0 : ((s < (unsigned int)(kNR + kNU)) ? 8 : 16);
            float2 q0 = bf2_to_f2(u[j].x), q1 = bf2_to_f2(u[j].y);
            float2 q2 = bf2_to_f2(u[j].z), q3 = bf2_to_f2(u[j].w);
            float* a = &agg_l[dloc * 29 + sb];
            atomicAdd(&a[0], q0.x); atomicAdd(&a[1], q0.y);
            atomicAdd(&a[2], q1.x); atomicAdd(&a[3], q1.y);
            atomicAdd(&a[4], q2.x); atomicAdd(&a[5], q2.y);
            atomicAdd(&a[6], q3.x); atomicAdd(&a[7], q3.y);
            atomicAdd(&agg_l[dloc * 29 + 24 + (sb >> 3)], 1.f);
        }
    }
    __syncthreads();   // pass-2 done; wst dead -> hbuf region live

    // ---- fused dense (MFMA): each wave handles one 16-node tile of this bucket ----
    int wid = tid >> 6, lane = tid & 63;
    int mm = lane & 15, q = lane >> 4;
    int node = wid * 16 + mm;
    bf16x8 a1;
    #pragma unroll
    for (int j = 0; j < 8; j++) {
        int sl = q * 8 + j;
        a1[j] = (sl < 27) ? (short)f_to_bf(agg_l[node * 29 + sl]) : (short)0;
    }
    f32x4 c1[8];
    #pragma unroll
    for (int t = 0; t < 8; t++) {
        bf16x8 bfr = *(const bf16x8*)&sfwT[(16 * t + mm) * 32 + q * 8];
        f32x4 z = {0.f, 0.f, 0.f, 0.f};
        c1[t] = __builtin_amdgcn_mfma_f32_16x16x32_bf16(a1, bfr, z, 0, 0, 0);
    }
    unsigned short* hb = hbuf + wid * 16 * 136;
    #pragma unroll
    for (int t = 0; t < 8; t++) {
        #pragma unroll
        for (int r = 0; r < 4; r++)
            hb[(q * 4 + r) * 136 + 16 * t + mm] = f_to_bf(fmaxf(c1[t][r], 0.f));
    }
    // same-wave LDS ordering: no barrier needed between hbuf write and read
    f32x4 c2[3];
    #pragma unroll
    for (int t = 0; t < 3; t++) { c2[t].x = 0.f; c2[t].y = 0.f; c2[t].z = 0.f; c2[t].w = 0.f; }
    #pragma unroll
    for (int s = 0; s < 4; s++) {
        bf16x8 a2 = *(const bf16x8*)&hb[mm * 136 + s * 32 + q * 8];
        #pragma unroll
        for (int t = 0; t < 3; t++) {
            bf16x8 b2 = *(const bf16x8*)&sw2T[(16 * t + mm) * 136 + s * 32 + q * 8];
            c2[t] = __builtin_amdgcn_mfma_f32_16x16x32_bf16(a2, b2, c2[t], 0, 0, 0);
        }
    }
    #pragma unroll
    for (int t = 0; t < 3; t++) {
        int cls = 16 * t + mm;
        if (cls < kC) {
            #pragma unroll
            for (int r = 0; r < 4; r++) {
                int n = base + wid * 16 + q * 4 + r;
                if (n < kN) hw[(size_t)n * kC + cls] = f_to_bf(c2[t][r]);
            }
        }
    }
}

// ---------- layer-2 gather: wave-per-node, 3 groups x 20 class-lanes, 4 rows in flight ----------
__global__ void __launch_bounds__(256) gcn_gather2(const unsigned int* __restrict__ hw32,
                                                   const int* __restrict__ rp,
                                                   const int* __restrict__ col,
                                                   unsigned int* __restrict__ out,
                                                   const int* __restrict__ flags) {
    int isbf = flags[0];
    int w = (blockIdx.x * 256 + threadIdx.x) >> 6;
    if (w >= kN) return;
    int lane = threadIdx.x & 63;
    int grp = lane / 20;
    int c2  = lane % 20;
    int beg = rp[w], end = rp[w + 1];
    float ax = 0.f, ay = 0.f;
    if (grp < 3) {
        int e = beg + grp;
        for (; e + 9 < end; e += 12) {
            int s0 = col[e], s1 = col[e + 3], s2 = col[e + 6], s3 = col[e + 9];
            float2 f0 = bf2_to_f2(hw32[s0 * 20 + c2]);
            float2 f1 = bf2_to_f2(hw32[s1 * 20 + c2]);
            float2 f2 = bf2_to_f2(hw32[s2 * 20 + c2]);
            float2 f3 = bf2_to_f2(hw32[s3 * 20 + c2]);
            ax += (f0.x + f1.x) + (f2.x + f3.x);
            ay += (f0.y + f1.y) + (f2.y + f3.y);
        }
        for (; e < end; e += 3) {
            float2 f = bf2_to_f2(hw32[col[e] * 20 + c2]);
            ax += f.x; ay += f.y;
        }
    }
    ax += __shfl(ax, lane + 20, 64) + __shfl(ax, lane + 40, 64);
    ay += __shfl(ay, lane + 20, 64) + __shfl(ay, lane + 40, 64);
    if (lane < 20) {
        if (isbf) {
            out[w * 20 + lane] = pack_bf2(ax, ay);
        } else {
            float* of = (float*)out;
            of[w * 40 + 2*lane]     = ax;
            of[w * 40 + 2*lane + 1] = ay;
        }
    }
}

extern "C" void kernel_launch(void* const* d_in, const int* in_sizes, int n_in,
                              void* d_out, int out_size, void* d_ws, size_t ws_size,
                              hipStream_t stream) {
    const void* xr = d_in[0];
    const void* xu = d_in[1];
    const void* xp = d_in[2];
    const int*  ei = (const int*)d_in[3];
    const void* Wr = d_in[4];
    const void* br = d_in[5];
    const void* Wu = d_in[6];
    const void* bu = d_in[7];
    const void* Wp = d_in[8];
    const void* bp = d_in[9];
    const void* W1 = d_in[10];
    const void* W2 = d_in[11];
    (void)in_sizes; (void)n_in; (void)out_size; (void)ws_size;

    char* ws = (char*)d_ws;
    size_t off = 0;
    auto alloc = [&](size_t bytes) -> void* {
        void* p = (void*)(ws + off);
        off = (off + bytes + 255) & ~(size_t)255;
        return p;
    };
    int*            flags  = (int*)           alloc(256);
    int*            cmat   = (int*)           alloc((size_t)kCH * kNBp * 4);  // 1.6 MB
    int*            reloff = (int*)           alloc((size_t)kNB * 256 * 4);   // 1.6 MB
    int*            btot   = (int*)           alloc((size_t)kNB * 4);
    int*            bbase  = (int*)           alloc((size_t)(kNB + 1) * 4);
    int*            rp     = (int*)           alloc((size_t)(kN + 1) * 4);
    unsigned short* fwT    = (unsigned short*)alloc(kF * 32 * 2);             // 8 KB
    uint4*          xpack  = (uint4*)         alloc((size_t)kN * 16);         // 1.6 MB
    unsigned int*   pairs  = (unsigned int*)  alloc((size_t)kE * 4);          // 6.4 MB
    int*            col    = (int*)           alloc((size_t)kE * 4);          // 6.4 MB
    unsigned short* hwb    = (unsigned short*)alloc((size_t)kN * kC * 2);     // 8 MB

    gcn_sniff<<<1, 64, 0, stream>>>((const unsigned int*)W1, ei, flags);
    gcn_setup<<<392, 256, 0, stream>>>(xr, xu, xp, Wr, br, Wu, bu, Wp, bp, W1,
                                       fwT, xpack, flags);
    gcn_count<<<kCH, 512, 0, stream>>>(ei, cmat, flags);
    gcn_scanB1<<<kNB, 256, 0, stream>>>(cmat, reloff, btot);
    gcn_scanB2<<<1, 512, 0, stream>>>(btot, bbase);
    gcn_scatter<<<kCH / kSG, 512, 0, stream>>>(ei, bbase, reloff, pairs, flags);
    GCN_2190433321521_kernel<<<kNB, 256, 0, stream>>>(pairs, bbase, xpack, fwT, W2,
                                                      rp, col, hwb, flags);
    gcn_gather2<<<(kN * 64 + 255) / 256, 256, 0, stream>>>((const unsigned int*)hwb, rp, col,
                                                           (unsigned int*)d_out, flags);
}

// Round 14
// 302.944 us; speedup vs baseline: 1.1053x; 1.0773x over previous
//
#include <hip/hip_runtime.h>

constexpr int kNR = 40000;
constexpr int kNU = 30000;
constexpr int kNP = 30000;
constexpr int kN  = 100000;          // total nodes
constexpr int kE  = 1600000;         // edges
constexpr int kF  = 128;             // feature/hidden dim
constexpr int kC  = 40;              // classes
constexpr int kBN = 64;              // nodes per bucket
constexpr int kNB = (kN + kBN - 1) / kBN;   // 1563 buckets
constexpr int kNBp = 1600;           // padded bucket-count stride
constexpr int kCH = 256;             // edge chunks (count/scan granularity)
constexpr int kCE = kE / kCH;        // 6250 edges per chunk
constexpr int kSG = 4;               // chunks per scatter block (64 blocks)
constexpr int kStash = 2048;         // LDS pair-stash capacity (avg bucket 1024)

typedef __attribute__((ext_vector_type(8))) short bf16x8;   // MFMA A/B frag
typedef __attribute__((ext_vector_type(4))) float f32x4;    // MFMA C/D frag

// ---------- bf16 helpers ----------
__device__ __forceinline__ float bf_to_f(unsigned short h) {
    union { unsigned int i; float f; } u; u.i = ((unsigned int)h) << 16; return u.f;
}
__device__ __forceinline__ unsigned short f_to_bf(float f) {
    union { unsigned int i; float f; } u; u.f = f;
    unsigned int r = u.i + 0x7FFFu + ((u.i >> 16) & 1u);   // RNE
    return (unsigned short)(r >> 16);
}
__device__ __forceinline__ float2 bf2_to_f2(unsigned int p) {
    union { unsigned int i; float f; } lo, hi;
    lo.i = (p & 0xFFFFu) << 16;
    hi.i = p & 0xFFFF0000u;
    return make_float2(lo.f, hi.f);
}
__device__ __forceinline__ unsigned int pack_bf2(float a, float b) {
    return (unsigned int)f_to_bf(a) | ((unsigned int)f_to_bf(b) << 16);
}
__device__ __forceinline__ float ldf(const void* p, int i, int isbf) {
    return isbf ? bf_to_f(((const unsigned short*)p)[i]) : ((const float*)p)[i];
}
__device__ __forceinline__ int lde(const int* p, int i, int is64) {
    return is64 ? p[2 * i] : p[i];
}

// ---------- sniff dtypes -> flags[0]=isbf, flags[1]=is64 ----------
__global__ void gcn_sniff(const unsigned int* __restrict__ w1w,
                          const int* __restrict__ eiw, int* __restrict__ flags) {
    if (blockIdx.x != 0 || threadIdx.x != 0) return;
    int plaus = 0;
    for (int k = 0; k < 64; k++) {
        unsigned int ax = w1w[k] & 0x7FFFu;
        plaus += (ax == 0u) || (ax > 0x2000u && ax < 0x4000u);
    }
    flags[0] = (plaus >= 48) ? 1 : 0;
    int nz = 0;
    for (int k = 0; k < 64; k++) nz |= eiw[2 * k + 1];
    flags[1] = (nz == 0) ? 1 : 0;
}

// ---------- setup ----------
// blocks 0..390: pack features. block 391: fuse weights -> fwfrag (frag-order).
// block 392: W2 -> w2frag (frag-order).
// fwfrag[t*64+lane][8]: B-frag for layer-1 tile t. w2frag[(s*3+t)*64+lane][8]: layer-2.
__global__ void __launch_bounds__(256) gcn_setup(
        const void* __restrict__ xr, const void* __restrict__ xu, const void* __restrict__ xp,
        const void* __restrict__ Wr, const void* __restrict__ br,
        const void* __restrict__ Wu, const void* __restrict__ bu,
        const void* __restrict__ Wp, const void* __restrict__ bp,
        const void* __restrict__ W1, const void* __restrict__ W2,
        unsigned short* __restrict__ fwfrag, unsigned short* __restrict__ w2frag,
        uint4* __restrict__ xpack, const int* __restrict__ flags) {
    int isbf = flags[0];
    int t = threadIdx.x;
    if (blockIdx.x == 391) {                 // ---- fuse -> fwfrag ----
        __shared__ float sw[21 * kF];              // 10.5 KB
        __shared__ unsigned short flds[kF * 32];   // 8 KB: fwT[feat][slot]
        for (int i = t; i < 21 * kF; i += 256) {
            int r = i >> 7, c = i & 127;
            float v;
            if (r < 5)        v = ldf(Wr, r * kF + c, isbf);
            else if (r < 12)  v = ldf(Wu, (r - 5) * kF + c, isbf);
            else if (r < 18)  v = ldf(Wp, (r - 12) * kF + c, isbf);
            else if (r == 18) v = ldf(br, c, isbf);
            else if (r == 19) v = ldf(bu, c, isbf);
            else              v = ldf(bp, c, isbf);
            sw[i] = v;
        }
        __syncthreads();
        if (t < 128) {
            int j = t;
            float acc[21];
            #pragma unroll
            for (int r = 0; r < 21; r++) acc[r] = 0.f;
            for (int k = 0; k < kF; k++) {
                float w1 = ldf(W1, k * kF + j, isbf);
                #pragma unroll
                for (int r = 0; r < 21; r++) acc[r] += sw[r * kF + k] * w1;
            }
            unsigned short row[32];
            #pragma unroll
            for (int s = 0; s < 32; s++) row[s] = 0;
            #pragma unroll
            for (int i = 0; i < 5; i++) row[0  + i] = f_to_bf(acc[i]);
            #pragma unroll
            for (int i = 0; i < 7; i++) row[8  + i] = f_to_bf(acc[5 + i]);
            #pragma unroll
            for (int i = 0; i < 6; i++) row[16 + i] = f_to_bf(acc[12 + i]);
            row[24] = f_to_bf(acc[18]);  row[25] = f_to_bf(acc[19]);  row[26] = f_to_bf(acc[20]);
            #pragma unroll
            for (int s = 0; s < 32; s++) flds[j * 32 + s] = row[s];
        }
        __syncthreads();
        // emit frag-order: fwfrag[(t8*64+lane)*8 + j] = fwT[(16*t8+mm)*32 + q*8 + j]
        for (int idx = t; idx < 8 * 64; idx += 256) {
            int t8 = idx >> 6, lane = idx & 63;
            int mm = lane & 15, q = lane >> 4;
            #pragma unroll
            for (int j = 0; j < 8; j++)
                fwfrag[idx * 8 + j] = flds[(16 * t8 + mm) * 32 + q * 8 + j];
        }
    } else if (blockIdx.x == 392) {          // ---- W2 -> w2frag ----
        // w2frag[((s*3+t)*64+lane)*8 + j] = bf16(W2[(s*32+q*8+j)*40 + 16t+mm])
        for (int idx = t; idx < 12 * 64; idx += 256) {
            int st = idx >> 6, lane = idx & 63;
            int s = st / 3, tt = st % 3;
            int mm = lane & 15, q = lane >> 4;
            int cls = 16 * tt + mm;
            #pragma unroll
            for (int j = 0; j < 8; j++) {
                int k = s * 32 + q * 8 + j;
                w2frag[idx * 8 + j] = (cls < kC) ? f_to_bf(ldf(W2, k * kC + cls, isbf))
                                                 : (unsigned short)0;
            }
        }
    } else {                                 // ---- pack ----
        int n = blockIdx.x * 256 + t;
        if (n >= kN) return;
        const void* base; int roff, d;
        if (n < kNR)            { base = xr; roff = n * 5;               d = 5; }
        else if (n < kNR + kNU) { base = xu; roff = (n - kNR) * 7;       d = 7; }
        else                    { base = xp; roff = (n - kNR - kNU) * 6; d = 6; }
        float f[8];
        #pragma unroll
        for (int i = 0; i < 8; i++) f[i] = (i < d) ? ldf(base, roff + i, isbf) : 0.f;
        uint4 u;
        u.x = pack_bf2(f[0], f[1]);  u.y = pack_bf2(f[2], f[3]);
        u.z = pack_bf2(f[4], f[5]);  u.w = pack_bf2(f[6], f[7]);
        xpack[n] = u;
    }
}

// ---------- multisplit pass 1: per-chunk bucket counts ----------
__global__ void __launch_bounds__(512) gcn_count(const int* __restrict__ ei,
                                                 int* __restrict__ cmat,
                                                 const int* __restrict__ flags) {
    __shared__ int cl[kNBp];
    int is64 = flags[1];
    int blk = blockIdx.x, t = threadIdx.x;
    for (int i = t; i < kNBp; i += 512) cl[i] = 0;
    __syncthreads();
    int e0 = blk * kCE, e1 = e0 + kCE;
    for (int eb = e0 + t; eb < e1; eb += 2048) {
        unsigned int d[4]; int ok[4];
        #pragma unroll
        for (int j = 0; j < 4; j++) {
            int e = eb + j * 512;
            ok[j] = (e < e1);
            d[j] = ok[j] ? (unsigned int)lde(ei, kE + e, is64) : 0u;
        }
        #pragma unroll
        for (int j = 0; j < 4; j++)
            if (ok[j] && d[j] < (unsigned int)kN) atomicAdd(&cl[d[j] >> 6], 1);
    }
    __syncthreads();
    for (int i = t; i < kNBp; i += 512) cmat[blk * kNBp + i] = cl[i];
}

// ---------- pass 2a: per-bucket scan over chunks ----------
__global__ void gcn_scanB1(const int* __restrict__ cmat, int* __restrict__ reloff,
                           int* __restrict__ btot) {
    __shared__ int lds[256];
    int b = blockIdx.x, t = threadIdx.x;
    int v = cmat[t * kNBp + b];
    int incl = v; lds[t] = incl; __syncthreads();
    for (int o = 1; o < 256; o <<= 1) {
        int y = (t >= o) ? lds[t - o] : 0;
        __syncthreads();
        incl += y; lds[t] = incl;
        __syncthreads();
    }
    reloff[b * 256 + t] = incl - v;
    if (t == 255) btot[b] = incl;
}

// ---------- pass 2b: scan bucket totals -> bbase ----------
__global__ void gcn_scanB2(const int* __restrict__ btot, int* __restrict__ bbase) {
    __shared__ int lds[512];
    int t = threadIdx.x;
    int v[4]; int s = 0;
    #pragma unroll
    for (int j = 0; j < 4; j++) {
        int i = 4 * t + j;
        v[j] = (i < kNB) ? btot[i] : 0;
        s += v[j];
    }
    int incl = s; lds[t] = incl; __syncthreads();
    for (int o = 1; o < 512; o <<= 1) {
        int y = (t >= o) ? lds[t - o] : 0;
        __syncthreads();
        incl += y; lds[t] = incl;
        __syncthreads();
    }
    int excl = incl - s;
    #pragma unroll
    for (int j = 0; j < 4; j++) {
        int i = 4 * t + j;
        if (i < kNB) { bbase[i] = excl; excl += v[j]; }
    }
    if (t == 511) bbase[kNB] = incl;
}

// ---------- pass 3: scatter pairs; 64 blocks x 4 consecutive chunks ----------
__global__ void __launch_bounds__(512) gcn_scatter(const int* __restrict__ ei,
                                                   const int* __restrict__ bbase,
                                                   const int* __restrict__ reloff,
                                                   unsigned int* __restrict__ pairs,
                                                   const int* __restrict__ flags) {
    __shared__ int cur[kNB];
    int is64 = flags[1];
    int blk = blockIdx.x, t = threadIdx.x;
    int c0 = blk * kSG;
    for (int i = t; i < kNB; i += 512) cur[i] = bbase[i] + reloff[i * 256 + c0];
    __syncthreads();
    int e0 = c0 * kCE, e1 = e0 + kSG * kCE;
    for (int eb = e0 + t; eb < e1; eb += 2048) {
        unsigned int d[4], s[4]; int ok[4];
        #pragma unroll
        for (int j = 0; j < 4; j++) {
            int e = eb + j * 512;
            ok[j] = (e < e1);
            d[j] = ok[j] ? (unsigned int)lde(ei, kE + e, is64) : 0xFFFFFFFFu;
        }
        #pragma unroll
        for (int j = 0; j < 4; j++) {
            int e = eb + j * 512;
            s[j] = ok[j] ? (unsigned int)lde(ei, e, is64) : 0u;
        }
        #pragma unroll
        for (int j = 0; j < 4; j++) {
            if (d[j] < (unsigned int)kN) {
                unsigned int sv = (s[j] < (unsigned int)kN) ? s[j] : 0u;
                int p = atomicAdd(&cur[d[j] >> 6], 1);
                pairs[p] = (sv << 6) | (d[j] & 63u);
            }
        }
    }
}

// ---------- MEGA bucket kernel: CSR build + layer-1 agg + fused MFMA dense ----------
// LDS now 25.3KB (B-operands come from L1-hot global frag tables) -> 4+ blocks/CU.
__global__ void __launch_bounds__(256) GCN_2190433321521_kernel(
        const unsigned int* __restrict__ pairs,
        const int* __restrict__ bbase,
        const uint4* __restrict__ xpack,
        const unsigned short* __restrict__ fwfrag,
        const unsigned short* __restrict__ w2frag,
        int* __restrict__ rp,
        int* __restrict__ col,
        unsigned short* __restrict__ hw,
        const int* __restrict__ flags) {
    __shared__ __align__(16) char smem[7424 + 256 + 256 + 17408];   // 25.3 KB
    float*          agg_l  = (float*)smem;                       // [64][29] fp32
    int*            cnt_l  = (int*)(smem + 7424);                // [64]
    int*            scan_l = (int*)(smem + 7424 + 256);          // [64]
    unsigned short* hbuf   = (unsigned short*)(smem + 7936);     // [4][16][136] bf16
    unsigned int*   wst    = (unsigned int*)(smem + 7936);       // pair stash [2048] (aliases hbuf)

    int b = blockIdx.x;
    int base = b * kBN;
    int nn = min(kBN, kN - base);
    int tid = threadIdx.x;
    (void)flags;

    for (int i = tid; i < kBN * 29; i += 256) agg_l[i] = 0.f;
    if (tid < kBN) cnt_l[tid] = 0;
    __syncthreads();
    int p0 = bbase[b], p1 = bbase[b + 1];
    int m = p1 - p0;
    bool fits = (m <= kStash);

    // pass 1: load pairs once -> stash + per-node histogram
    for (int ib = p0 + tid; ib < p1; ib += 1024) {
        unsigned int w[4]; int ok[4];
        #pragma unroll
        for (int j = 0; j < 4; j++) {
            int i = ib + j * 256;
            ok[j] = (i < p1);
            w[j] = ok[j] ? pairs[i] : 0u;
        }
        #pragma unroll
        for (int j = 0; j < 4; j++) {
            int i = ib + j * 256;
            if (ok[j]) {
                if (fits) wst[i - p0] = w[j];
                atomicAdd(&cnt_l[w[j] & 63u], 1);
            }
        }
    }
    __syncthreads();
    // scan 64 node-counts -> cursors + rp
    int v = (tid < kBN) ? cnt_l[tid] : 0;
    int incl = v;
    if (tid < kBN) scan_l[tid] = incl;
    __syncthreads();
    for (int o = 1; o < kBN; o <<= 1) {
        int y = (tid < kBN && tid >= o) ? scan_l[tid - o] : 0;
        __syncthreads();
        if (tid < kBN) { incl += y; scan_l[tid] = incl; }
        __syncthreads();
    }
    if (tid < kBN) {
        int cursor = p0 + incl - v;
        cnt_l[tid] = cursor;
        if (tid < nn) rp[base + tid] = cursor;
    }
    if (b == kNB - 1 && tid == 0) rp[kN] = p1;
    __syncthreads();

    // pass 2: col build + agg accumulate
    for (int ib = p0 + tid; ib < p1; ib += 1024) {
        unsigned int w[4]; uint4 u[4]; int ok[4];
        #pragma unroll
        for (int j = 0; j < 4; j++) {
            int i = ib + j * 256;
            ok[j] = (i < p1);
            w[j] = ok[j] ? (fits ? wst[i - p0] : pairs[i]) : 0u;
        }
        #pragma unroll
        for (int j = 0; j < 4; j++)
            if (ok[j]) u[j] = xpack[w[j] >> 6];
        #pragma unroll
        for (int j = 0; j < 4; j++) {
            if (!ok[j]) continue;
            unsigned int s = w[j] >> 6;
            int dloc = (int)(w[j] & 63u);
            int pos = atomicAdd(&cnt_l[dloc], 1);
            col[pos] = (int)s;
            int sb = (s < (unsigned int)kNR) ? 0 : ((s < (unsigned int)(kNR + kNU)) ? 8 : 16);
            float2 q0 = bf2_to_f2(u[j].x), q1 = bf2_to_f2(u[j].y);
            float2 q2 = bf2_to_f2(u[j].z), q3 = bf2_to_f2(u[j].w);
            float* a = &agg_l[dloc * 29 + sb];
            atomicAdd(&a[0], q0.x); atomicAdd(&a[1], q0.y);
            atomicAdd(&a[2], q1.x); atomicAdd(&a[3], q1.y);
            atomicAdd(&a[4], q2.x); atomicAdd(&a[5], q2.y);
            atomicAdd(&a[6], q3.x); atomicAdd(&a[7], q3.y);
            atomicAdd(&agg_l[dloc * 29 + 24 + (sb >> 3)], 1.f);
        }
    }
    __syncthreads();   // pass-2 done; wst dead -> hbuf region live

    // ---- fused dense (MFMA): each wave = one 16-node tile; B-frags from global (L1-hot) ----
    int wid = tid >> 6, lane = tid & 63;
    int mm = lane & 15, q = lane >> 4;
    int node = wid * 16 + mm;
    bf16x8 a1;
    #pragma unroll
    for (int j = 0; j < 8; j++) {
        int sl = q * 8 + j;
        a1[j] = (sl < 27) ? (short)f_to_bf(agg_l[node * 29 + sl]) : (short)0;
    }
    const bf16x8* fwf = (const bf16x8*)fwfrag;
    f32x4 c1[8];
    #pragma unroll
    for (int t = 0; t < 8; t++) {
        f32x4 z = {0.f, 0.f, 0.f, 0.f};
        c1[t] = __builtin_amdgcn_mfma_f32_16x16x32_bf16(a1, fwf[t * 64 + lane], z, 0, 0, 0);
    }
    unsigned short* hb = hbuf + wid * 16 * 136;
    #pragma unroll
    for (int t = 0; t < 8; t++) {
        #pragma unroll
        for (int r = 0; r < 4; r++)
            hb[(q * 4 + r) * 136 + 16 * t + mm] = f_to_bf(fmaxf(c1[t][r], 0.f));
    }
    // same-wave LDS ordering: no barrier needed between hbuf write and read
    const bf16x8* w2f = (const bf16x8*)w2frag;
    f32x4 c2[3];
    #pragma unroll
    for (int t = 0; t < 3; t++) { c2[t].x = 0.f; c2[t].y = 0.f; c2[t].z = 0.f; c2[t].w = 0.f; }
    #pragma unroll
    for (int s = 0; s < 4; s++) {
        bf16x8 a2 = *(const bf16x8*)&hb[mm * 136 + s * 32 + q * 8];
        #pragma unroll
        for (int t = 0; t < 3; t++)
            c2[t] = __builtin_amdgcn_mfma_f32_16x16x32_bf16(a2, w2f[(s * 3 + t) * 64 + lane],
                                                            c2[t], 0, 0, 0);
    }
    #pragma unroll
    for (int t = 0; t < 3; t++) {
        int cls = 16 * t + mm;
        if (cls < kC) {
            #pragma unroll
            for (int r = 0; r < 4; r++) {
                int n = base + wid * 16 + q * 4 + r;
                if (n < kN) hw[(size_t)n * kC + cls] = f_to_bf(c2[t][r]);
            }
        }
    }
}

// ---------- layer-2 gather: wave-per-node, 3 groups x 20 class-lanes, 4 rows in flight ----------
__global__ void __launch_bounds__(256) gcn_gather2(const unsigned int* __restrict__ hw32,
                                                   const int* __restrict__ rp,
                                                   const int* __restrict__ col,
                                                   unsigned int* __restrict__ out,
                                                   const int* __restrict__ flags) {
    int isbf = flags[0];
    int w = (blockIdx.x * 256 + threadIdx.x) >> 6;
    if (w >= kN) return;
    int lane = threadIdx.x & 63;
    int grp = lane / 20;
    int c2  = lane % 20;
    int beg = rp[w], end = rp[w + 1];
    float ax = 0.f, ay = 0.f;
    if (grp < 3) {
        int e = beg + grp;
        for (; e + 9 < end; e += 12) {
            int s0 = col[e], s1 = col[e + 3], s2 = col[e + 6], s3 = col[e + 9];
            float2 f0 = bf2_to_f2(hw32[s0 * 20 + c2]);
            float2 f1 = bf2_to_f2(hw32[s1 * 20 + c2]);
            float2 f2 = bf2_to_f2(hw32[s2 * 20 + c2]);
            float2 f3 = bf2_to_f2(hw32[s3 * 20 + c2]);
            ax += (f0.x + f1.x) + (f2.x + f3.x);
            ay += (f0.y + f1.y) + (f2.y + f3.y);
        }
        for (; e < end; e += 3) {
            float2 f = bf2_to_f2(hw32[col[e] * 20 + c2]);
            ax += f.x; ay += f.y;
        }
    }
    ax += __shfl(ax, lane + 20, 64) + __shfl(ax, lane + 40, 64);
    ay += __shfl(ay, lane + 20, 64) + __shfl(ay, lane + 40, 64);
    if (lane < 20) {
        if (isbf) {
            out[w * 20 + lane] = pack_bf2(ax, ay);
        } else {
            float* of = (float*)out;
            of[w * 40 + 2*lane]     = ax;
            of[w * 40 + 2*lane + 1] = ay;
        }
    }
}

extern "C" void kernel_launch(void* const* d_in, const int* in_sizes, int n_in,
                              void* d_out, int out_size, void* d_ws, size_t ws_size,
                              hipStream_t stream) {
    const void* xr = d_in[0];
    const void* xu = d_in[1];
    const void* xp = d_in[2];
    const int*  ei = (const int*)d_in[3];
    const void* Wr = d_in[4];
    const void* br = d_in[5];
    const void* Wu = d_in[6];
    const void* bu = d_in[7];
    const void* Wp = d_in[8];
    const void* bp = d_in[9];
    const void* W1 = d_in[10];
    const void* W2 = d_in[11];
    (void)in_sizes; (void)n_in; (void)out_size; (void)ws_size;

    char* ws = (char*)d_ws;
    size_t off = 0;
    auto alloc = [&](size_t bytes) -> void* {
        void* p = (void*)(ws + off);
        off = (off + bytes + 255) & ~(size_t)255;
        return p;
    };
    int*            flags  = (int*)           alloc(256);
    int*            cmat   = (int*)           alloc((size_t)kCH * kNBp * 4);  // 1.6 MB
    int*            reloff = (int*)           alloc((size_t)kNB * 256 * 4);   // 1.6 MB
    int*            btot   = (int*)           alloc((size_t)kNB * 4);
    int*            bbase  = (int*)           alloc((size_t)(kNB + 1) * 4);
    int*            rp     = (int*)           alloc((size_t)(kN + 1) * 4);
    unsigned short* fwfrag = (unsigned short*)alloc(8 * 64 * 8 * 2);          // 8 KB
    unsigned short* w2frag = (unsigned short*)alloc(12 * 64 * 8 * 2);         // 12 KB
    uint4*          xpack  = (uint4*)         alloc((size_t)kN * 16);         // 1.6 MB
    unsigned int*   pairs  = (unsigned int*)  alloc((size_t)kE * 4);          // 6.4 MB
    int*            col    = (int*)           alloc((size_t)kE * 4);          // 6.4 MB
    unsigned short* hwb    = (unsigned short*)alloc((size_t)kN * kC * 2);     // 8 MB

    gcn_sniff<<<1, 64, 0, stream>>>((const unsigned int*)W1, ei, flags);
    gcn_setup<<<393, 256, 0, stream>>>(xr, xu, xp, Wr, br, Wu, bu, Wp, bp, W1, W2,
                                       fwfrag, w2frag, xpack, flags);
    gcn_count<<<kCH, 512, 0, stream>>>(ei, cmat, flags);
    gcn_scanB1<<<kNB, 256, 0, stream>>>(cmat, reloff, btot);
    gcn_scanB2<<<1, 512, 0, stream>>>(btot, bbase);
    gcn_scatter<<<kCH / kSG, 512, 0, stream>>>(ei, bbase, reloff, pairs, flags);
    GCN_2190433321521_kernel<<<kNB, 256, 0, stream>>>(pairs, bbase, xpack, fwfrag, w2frag,
                                                      rp, col, hwb, flags);
    gcn_gather2<<<(kN * 64 + 255) / 256, 256, 0, stream>>>((const unsigned int*)hwb, rp, col,
                                                           (unsigned int*)d_out, flags);
}

// Round 15
// 243.083 us; speedup vs baseline: 1.3774x; 1.2463x over previous
//
#include <hip/hip_runtime.h>

constexpr int kNR = 40000;
constexpr int kNU = 30000;
constexpr int kNP = 30000;
constexpr int kN  = 100000;          // total nodes
constexpr int kE  = 1600000;         // edges
constexpr int kF  = 128;             // feature/hidden dim
constexpr int kC  = 40;              // classes
constexpr int kBN = 64;              // nodes per bucket
constexpr int kNB = (kN + kBN - 1) / kBN;   // 1563 buckets
constexpr int kNBp = 1600;           // padded bucket-count stride
constexpr int kCH = 256;             // edge chunks (count/scan granularity)
constexpr int kCE = kE / kCH;        // 6250 edges per chunk
constexpr int kSG = 4;               // chunks per scatter block (64 blocks)
constexpr int kStash = 2048;         // LDS pair-stash capacity (avg bucket 1024)

typedef __attribute__((ext_vector_type(8))) short bf16x8;   // MFMA A/B frag
typedef __attribute__((ext_vector_type(4))) float f32x4;    // MFMA C/D frag

// ---------- bf16 helpers ----------
__device__ __forceinline__ float bf_to_f(unsigned short h) {
    union { unsigned int i; float f; } u; u.i = ((unsigned int)h) << 16; return u.f;
}
__device__ __forceinline__ unsigned short f_to_bf(float f) {
    union { unsigned int i; float f; } u; u.f = f;
    unsigned int r = u.i + 0x7FFFu + ((u.i >> 16) & 1u);   // RNE
    return (unsigned short)(r >> 16);
}
__device__ __forceinline__ float2 bf2_to_f2(unsigned int p) {
    union { unsigned int i; float f; } lo, hi;
    lo.i = (p & 0xFFFFu) << 16;
    hi.i = p & 0xFFFF0000u;
    return make_float2(lo.f, hi.f);
}
__device__ __forceinline__ unsigned int pack_bf2(float a, float b) {
    return (unsigned int)f_to_bf(a) | ((unsigned int)f_to_bf(b) << 16);
}
__device__ __forceinline__ float ldf(const void* p, int i, int isbf) {
    return isbf ? bf_to_f(((const unsigned short*)p)[i]) : ((const float*)p)[i];
}
__device__ __forceinline__ int lde(const int* p, int i, int is64) {
    return is64 ? p[2 * i] : p[i];
}

// ---------- sniff dtypes -> flags[0]=isbf, flags[1]=is64 ----------
__global__ void gcn_sniff(const unsigned int* __restrict__ w1w,
                          const int* __restrict__ eiw, int* __restrict__ flags) {
    if (blockIdx.x != 0 || threadIdx.x != 0) return;
    int plaus = 0;
    for (int k = 0; k < 64; k++) {
        unsigned int ax = w1w[k] & 0x7FFFu;
        plaus += (ax == 0u) || (ax > 0x2000u && ax < 0x4000u);
    }
    flags[0] = (plaus >= 48) ? 1 : 0;
    int nz = 0;
    for (int k = 0; k < 64; k++) nz |= eiw[2 * k + 1];
    flags[1] = (nz == 0) ? 1 : 0;
}

// ---------- setup: pack features + frag-order weight tables (verified R14) ----------
__global__ void __launch_bounds__(256) gcn_setup(
        const void* __restrict__ xr, const void* __restrict__ xu, const void* __restrict__ xp,
        const void* __restrict__ Wr, const void* __restrict__ br,
        const void* __restrict__ Wu, const void* __restrict__ bu,
        const void* __restrict__ Wp, const void* __restrict__ bp,
        const void* __restrict__ W1, const void* __restrict__ W2,
        unsigned short* __restrict__ fwfrag, unsigned short* __restrict__ w2frag,
        uint4* __restrict__ xpack, const int* __restrict__ flags) {
    int isbf = flags[0];
    int t = threadIdx.x;
    if (blockIdx.x == 391) {                 // ---- fuse -> fwfrag ----
        __shared__ float sw[21 * kF];
        __shared__ unsigned short flds[kF * 32];
        for (int i = t; i < 21 * kF; i += 256) {
            int r = i >> 7, c = i & 127;
            float v;
            if (r < 5)        v = ldf(Wr, r * kF + c, isbf);
            else if (r < 12)  v = ldf(Wu, (r - 5) * kF + c, isbf);
            else if (r < 18)  v = ldf(Wp, (r - 12) * kF + c, isbf);
            else if (r == 18) v = ldf(br, c, isbf);
            else if (r == 19) v = ldf(bu, c, isbf);
            else              v = ldf(bp, c, isbf);
            sw[i] = v;
        }
        __syncthreads();
        if (t < 128) {
            int j = t;
            float acc[21];
            #pragma unroll
            for (int r = 0; r < 21; r++) acc[r] = 0.f;
            for (int k = 0; k < kF; k++) {
                float w1 = ldf(W1, k * kF + j, isbf);
                #pragma unroll
                for (int r = 0; r < 21; r++) acc[r] += sw[r * kF + k] * w1;
            }
            unsigned short row[32];
            #pragma unroll
            for (int s = 0; s < 32; s++) row[s] = 0;
            #pragma unroll
            for (int i = 0; i < 5; i++) row[0  + i] = f_to_bf(acc[i]);
            #pragma unroll
            for (int i = 0; i < 7; i++) row[8  + i] = f_to_bf(acc[5 + i]);
            #pragma unroll
            for (int i = 0; i < 6; i++) row[16 + i] = f_to_bf(acc[12 + i]);
            row[24] = f_to_bf(acc[18]);  row[25] = f_to_bf(acc[19]);  row[26] = f_to_bf(acc[20]);
            #pragma unroll
            for (int s = 0; s < 32; s++) flds[j * 32 + s] = row[s];
        }
        __syncthreads();
        for (int idx = t; idx < 8 * 64; idx += 256) {
            int t8 = idx >> 6, lane = idx & 63;
            int mm = lane & 15, q = lane >> 4;
            #pragma unroll
            for (int j = 0; j < 8; j++)
                fwfrag[idx * 8 + j] = flds[(16 * t8 + mm) * 32 + q * 8 + j];
        }
    } else if (blockIdx.x == 392) {          // ---- W2 -> w2frag ----
        for (int idx = t; idx < 12 * 64; idx += 256) {
            int st = idx >> 6, lane = idx & 63;
            int s = st / 3, tt = st % 3;
            int mm = lane & 15, q = lane >> 4;
            int cls = 16 * tt + mm;
            #pragma unroll
            for (int j = 0; j < 8; j++) {
                int k = s * 32 + q * 8 + j;
                w2frag[idx * 8 + j] = (cls < kC) ? f_to_bf(ldf(W2, k * kC + cls, isbf))
                                                 : (unsigned short)0;
            }
        }
    } else {                                 // ---- pack ----
        int n = blockIdx.x * 256 + t;
        if (n >= kN) return;
        const void* base; int roff, d;
        if (n < kNR)            { base = xr; roff = n * 5;               d = 5; }
        else if (n < kNR + kNU) { base = xu; roff = (n - kNR) * 7;       d = 7; }
        else                    { base = xp; roff = (n - kNR - kNU) * 6; d = 6; }
        float f[8];
        #pragma unroll
        for (int i = 0; i < 8; i++) f[i] = (i < d) ? ldf(base, roff + i, isbf) : 0.f;
        uint4 u;
        u.x = pack_bf2(f[0], f[1]);  u.y = pack_bf2(f[2], f[3]);
        u.z = pack_bf2(f[4], f[5]);  u.w = pack_bf2(f[6], f[7]);
        xpack[n] = u;
    }
}

// ---------- multisplit pass 1: per-chunk bucket counts ----------
__global__ void __launch_bounds__(512) gcn_count(const int* __restrict__ ei,
                                                 int* __restrict__ cmat,
                                                 const int* __restrict__ flags) {
    __shared__ int cl[kNBp];
    int is64 = flags[1];
    int blk = blockIdx.x, t = threadIdx.x;
    for (int i = t; i < kNBp; i += 512) cl[i] = 0;
    __syncthreads();
    int e0 = blk * kCE, e1 = e0 + kCE;
    for (int eb = e0 + t; eb < e1; eb += 2048) {
        unsigned int d[4]; int ok[4];
        #pragma unroll
        for (int j = 0; j < 4; j++) {
            int e = eb + j * 512;
            ok[j] = (e < e1);
            d[j] = ok[j] ? (unsigned int)lde(ei, kE + e, is64) : 0u;
        }
        #pragma unroll
        for (int j = 0; j < 4; j++)
            if (ok[j] && d[j] < (unsigned int)kN) atomicAdd(&cl[d[j] >> 6], 1);
    }
    __syncthreads();
    for (int i = t; i < kNBp; i += 512) cmat[blk * kNBp + i] = cl[i];
}

// ---------- pass 2a: per-bucket scan over chunks ----------
__global__ void gcn_scanB1(const int* __restrict__ cmat, int* __restrict__ reloff,
                           int* __restrict__ btot) {
    __shared__ int lds[256];
    int b = blockIdx.x, t = threadIdx.x;
    int v = cmat[t * kNBp + b];
    int incl = v; lds[t] = incl; __syncthreads();
    for (int o = 1; o < 256; o <<= 1) {
        int y = (t >= o) ? lds[t - o] : 0;
        __syncthreads();
        incl += y; lds[t] = incl;
        __syncthreads();
    }
    reloff[b * 256 + t] = incl - v;
    if (t == 255) btot[b] = incl;
}

// ---------- pass 2b: scan bucket totals -> bbase ----------
__global__ void gcn_scanB2(const int* __restrict__ btot, int* __restrict__ bbase) {
    __shared__ int lds[512];
    int t = threadIdx.x;
    int v[4]; int s = 0;
    #pragma unroll
    for (int j = 0; j < 4; j++) {
        int i = 4 * t + j;
        v[j] = (i < kNB) ? btot[i] : 0;
        s += v[j];
    }
    int incl = s; lds[t] = incl; __syncthreads();
    for (int o = 1; o < 512; o <<= 1) {
        int y = (t >= o) ? lds[t - o] : 0;
        __syncthreads();
        incl += y; lds[t] = incl;
        __syncthreads();
    }
    int excl = incl - s;
    #pragma unroll
    for (int j = 0; j < 4; j++) {
        int i = 4 * t + j;
        if (i < kNB) { bbase[i] = excl; excl += v[j]; }
    }
    if (t == 511) bbase[kNB] = incl;
}

// ---------- pass 3: scatter pairs; 64 blocks x 1024 threads (2x waves vs R14) ----------
__global__ void __launch_bounds__(1024) gcn_scatter(const int* __restrict__ ei,
                                                    const int* __restrict__ bbase,
                                                    const int* __restrict__ reloff,
                                                    unsigned int* __restrict__ pairs,
                                                    const int* __restrict__ flags) {
    __shared__ int cur[kNB];
    int is64 = flags[1];
    int blk = blockIdx.x, t = threadIdx.x;
    int c0 = blk * kSG;
    for (int i = t; i < kNB; i += 1024) cur[i] = bbase[i] + reloff[i * 256 + c0];
    __syncthreads();
    int e0 = c0 * kCE, e1 = e0 + kSG * kCE;
    for (int eb = e0 + t; eb < e1; eb += 4096) {
        unsigned int d[4], s[4]; int ok[4];
        #pragma unroll
        for (int j = 0; j < 4; j++) {
            int e = eb + j * 1024;
            ok[j] = (e < e1);
            d[j] = ok[j] ? (unsigned int)lde(ei, kE + e, is64) : 0xFFFFFFFFu;
        }
        #pragma unroll
        for (int j = 0; j < 4; j++) {
            int e = eb + j * 1024;
            s[j] = ok[j] ? (unsigned int)lde(ei, e, is64) : 0u;
        }
        #pragma unroll
        for (int j = 0; j < 4; j++) {
            if (d[j] < (unsigned int)kN) {
                unsigned int sv = (s[j] < (unsigned int)kN) ? s[j] : 0u;
                int p = atomicAdd(&cur[d[j] >> 6], 1);
                pairs[p] = (sv << 6) | (d[j] & 63u);
            }
        }
    }
}

// ---------- MEGA bucket kernel: CSR build + layer-1 agg (register acc) + MFMA dense ----------
// Pass2 split: 2a builds col (1 LDS atomic/edge); 2b has 4 threads/node accumulating
// all 27 agg slots in REGISTERS from the node-sorted col run, quad-shfl reduce, one
// non-atomic LDS store per slot. LDS atomics: 14.4M -> 3.2M total.
__global__ void __launch_bounds__(256) GCN_2190433321521_kernel(
        const unsigned int* __restrict__ pairs,
        const int* __restrict__ bbase,
        const uint4* __restrict__ xpack,
        const unsigned short* __restrict__ fwfrag,
        const unsigned short* __restrict__ w2frag,
        int* __restrict__ rp,
        int* __restrict__ col,
        unsigned short* __restrict__ hw,
        const int* __restrict__ flags) {
    __shared__ __align__(16) char smem[25600];
    float*          agg_l  = (float*)smem;                       // [64][29] fp32, 7424 B
    int*            cnt_l  = (int*)(smem + 7424);                // [64] working cursors
    int*            strt_l = (int*)(smem + 7680);                // [64] start cursors
    int*            cntv_l = (int*)(smem + 7936);                // [64] node counts
    unsigned int*   wst    = (unsigned int*)(smem + 8192);       // pair stash [2048], 8 KB
    int*            col_l  = (int*)(smem + 16384);               // col staging [2048], 8 KB
    unsigned short* hbuf   = (unsigned short*)(smem + 8192);     // [4][16][136] (aliases wst+col_l)

    int b = blockIdx.x;
    int base = b * kBN;
    int nn = min(kBN, kN - base);
    int tid = threadIdx.x;
    (void)flags;

    if (tid < kBN) cnt_l[tid] = 0;
    __syncthreads();
    int p0 = bbase[b], p1 = bbase[b + 1];
    int m = p1 - p0;
    bool fits = (m <= kStash);

    // pass 1: load pairs once -> stash + per-node histogram
    for (int ib = p0 + tid; ib < p1; ib += 1024) {
        unsigned int w[4]; int ok[4];
        #pragma unroll
        for (int j = 0; j < 4; j++) {
            int i = ib + j * 256;
            ok[j] = (i < p1);
            w[j] = ok[j] ? pairs[i] : 0u;
        }
        #pragma unroll
        for (int j = 0; j < 4; j++) {
            int i = ib + j * 256;
            if (ok[j]) {
                if (fits) wst[i - p0] = w[j];
                atomicAdd(&cnt_l[w[j] & 63u], 1);
            }
        }
    }
    __syncthreads();
    // scan 64 node-counts -> start cursors, counts, rp
    {
        int v = (tid < kBN) ? cnt_l[tid] : 0;
        int incl = v;
        if (tid < kBN) strt_l[tid] = incl;
        __syncthreads();
        for (int o = 1; o < kBN; o <<= 1) {
            int y = (tid < kBN && tid >= o) ? strt_l[tid - o] : 0;
            __syncthreads();
            if (tid < kBN) { incl += y; strt_l[tid] = incl; }
            __syncthreads();
        }
        if (tid < kBN) {
            int cursor = p0 + incl - v;            // global coords
            cnt_l[tid]  = cursor;                  // working cursor
            strt_l[tid] = cursor;                  // stable start
            cntv_l[tid] = v;
            if (tid < nn) rp[base + tid] = cursor;
        }
        if (b == kNB - 1 && tid == 0) rp[kN] = p1;
    }
    __syncthreads();

    // pass 2a: col build only (1 LDS atomic per edge)
    for (int i = p0 + tid; i < p1; i += 256) {
        unsigned int w = fits ? wst[i - p0] : pairs[i];
        unsigned int s = w >> 6;
        int dloc = (int)(w & 63u);
        int pos = atomicAdd(&cnt_l[dloc], 1);
        if (fits) col_l[pos - p0] = (int)s;
        else      col[pos] = (int)s;
    }
    __syncthreads();
    // flush col (coalesced) while 2b computes? do flush first (streaming store)
    if (fits) {
        for (int i = tid; i < m; i += 256) col[p0 + i] = col_l[i];
    }

    // pass 2b: 4 threads per node; register accumulation of 27 slots
    {
        int node = tid >> 2, j = tid & 3;
        float aR[8], aU[8], aP[8];
        #pragma unroll
        for (int i = 0; i < 8; i++) { aR[i] = 0.f; aU[i] = 0.f; aP[i] = 0.f; }
        float cR = 0.f, cU = 0.f, cP = 0.f;
        int start = strt_l[node] - p0;     // local index into col_l / col
        int c = cntv_l[node];
        for (int i = start + j; i < start + c; i += 4) {
            int s = fits ? col_l[i] : col[p0 + i];
            uint4 u = xpack[s];
            float2 q0 = bf2_to_f2(u.x), q1 = bf2_to_f2(u.y);
            float2 q2 = bf2_to_f2(u.z), q3 = bf2_to_f2(u.w);
            if (s < kNR) {
                aR[0]+=q0.x; aR[1]+=q0.y; aR[2]+=q1.x; aR[3]+=q1.y;
                aR[4]+=q2.x; aR[5]+=q2.y; aR[6]+=q3.x; aR[7]+=q3.y; cR += 1.f;
            } else if (s < kNR + kNU) {
                aU[0]+=q0.x; aU[1]+=q0.y; aU[2]+=q1.x; aU[3]+=q1.y;
                aU[4]+=q2.x; aU[5]+=q2.y; aU[6]+=q3.x; aU[7]+=q3.y; cU += 1.f;
            } else {
                aP[0]+=q0.x; aP[1]+=q0.y; aP[2]+=q1.x; aP[3]+=q1.y;
                aP[4]+=q2.x; aP[5]+=q2.y; aP[6]+=q3.x; aP[7]+=q3.y; cP += 1.f;
            }
        }
        // quad reduction (lanes 4k..4k+3 are the same node) + non-atomic store
        #pragma unroll
        for (int i = 0; i < 8; i++) {
            float v = aR[i];
            v += __shfl_xor(v, 1, 64);  v += __shfl_xor(v, 2, 64);
            if (j == 0) agg_l[node * 29 + i] = v;
        }
        #pragma unroll
        for (int i = 0; i < 8; i++) {
            float v = aU[i];
            v += __shfl_xor(v, 1, 64);  v += __shfl_xor(v, 2, 64);
            if (j == 0) agg_l[node * 29 + 8 + i] = v;
        }
        #pragma unroll
        for (int i = 0; i < 8; i++) {
            float v = aP[i];
            v += __shfl_xor(v, 1, 64);  v += __shfl_xor(v, 2, 64);
            if (j == 0) agg_l[node * 29 + 16 + i] = v;
        }
        float v = cR;
        v += __shfl_xor(v, 1, 64);  v += __shfl_xor(v, 2, 64);
        if (j == 0) agg_l[node * 29 + 24] = v;
        v = cU;
        v += __shfl_xor(v, 1, 64);  v += __shfl_xor(v, 2, 64);
        if (j == 0) agg_l[node * 29 + 25] = v;
        v = cP;
        v += __shfl_xor(v, 1, 64);  v += __shfl_xor(v, 2, 64);
        if (j == 0) agg_l[node * 29 + 26] = v;
    }
    __syncthreads();   // agg_l complete; wst/col_l dead -> hbuf region live

    // ---- fused dense (MFMA): each wave = one 16-node tile; B-frags from global ----
    int wid = tid >> 6, lane = tid & 63;
    int mm = lane & 15, q = lane >> 4;
    int node = wid * 16 + mm;
    bf16x8 a1;
    #pragma unroll
    for (int j = 0; j < 8; j++) {
        int sl = q * 8 + j;
        a1[j] = (sl < 27) ? (short)f_to_bf(agg_l[node * 29 + sl]) : (short)0;
    }
    const bf16x8* fwf = (const bf16x8*)fwfrag;
    f32x4 c1[8];
    #pragma unroll
    for (int t = 0; t < 8; t++) {
        f32x4 z = {0.f, 0.f, 0.f, 0.f};
        c1[t] = __builtin_amdgcn_mfma_f32_16x16x32_bf16(a1, fwf[t * 64 + lane], z, 0, 0, 0);
    }
    unsigned short* hb = hbuf + wid * 16 * 136;
    #pragma unroll
    for (int t = 0; t < 8; t++) {
        #pragma unroll
        for (int r = 0; r < 4; r++)
            hb[(q * 4 + r) * 136 + 16 * t + mm] = f_to_bf(fmaxf(c1[t][r], 0.f));
    }
    const bf16x8* w2f = (const bf16x8*)w2frag;
    f32x4 c2[3];
    #pragma unroll
    for (int t = 0; t < 3; t++) { c2[t].x = 0.f; c2[t].y = 0.f; c2[t].z = 0.f; c2[t].w = 0.f; }
    #pragma unroll
    for (int s = 0; s < 4; s++) {
        bf16x8 a2 = *(const bf16x8*)&hb[mm * 136 + s * 32 + q * 8];
        #pragma unroll
        for (int t = 0; t < 3; t++)
            c2[t] = __builtin_amdgcn_mfma_f32_16x16x32_bf16(a2, w2f[(s * 3 + t) * 64 + lane],
                                                            c2[t], 0, 0, 0);
    }
    #pragma unroll
    for (int t = 0; t < 3; t++) {
        int cls = 16 * t + mm;
        if (cls < kC) {
            #pragma unroll
            for (int r = 0; r < 4; r++) {
                int n = base + wid * 16 + q * 4 + r;
                if (n < kN) hw[(size_t)n * kC + cls] = f_to_bf(c2[t][r]);
            }
        }
    }
}

// ---------- layer-2 gather: wave-per-node, 3 groups x 20 class-lanes, 4 rows in flight ----------
__global__ void __launch_bounds__(256) gcn_gather2(const unsigned int* __restrict__ hw32,
                                                   const int* __restrict__ rp,
                                                   const int* __restrict__ col,
                                                   unsigned int* __restrict__ out,
                                                   const int* __restrict__ flags) {
    int isbf = flags[0];
    int w = (blockIdx.x * 256 + threadIdx.x) >> 6;
    if (w >= kN) return;
    int lane = threadIdx.x & 63;
    int grp = lane / 20;
    int c2  = lane % 20;
    int beg = rp[w], end = rp[w + 1];
    float ax = 0.f, ay = 0.f;
    if (grp < 3) {
        int e = beg + grp;
        for (; e + 9 < end; e += 12) {
            int s0 = col[e], s1 = col[e + 3], s2 = col[e + 6], s3 = col[e + 9];
            float2 f0 = bf2_to_f2(hw32[s0 * 20 + c2]);
            float2 f1 = bf2_to_f2(hw32[s1 * 20 + c2]);
            float2 f2 = bf2_to_f2(hw32[s2 * 20 + c2]);
            float2 f3 = bf2_to_f2(hw32[s3 * 20 + c2]);
            ax += (f0.x + f1.x) + (f2.x + f3.x);
            ay += (f0.y + f1.y) + (f2.y + f3.y);
        }
        for (; e < end; e += 3) {
            float2 f = bf2_to_f2(hw32[col[e] * 20 + c2]);
            ax += f.x; ay += f.y;
        }
    }
    ax += __shfl(ax, lane + 20, 64) + __shfl(ax, lane + 40, 64);
    ay += __shfl(ay, lane + 20, 64) + __shfl(ay, lane + 40, 64);
    if (lane < 20) {
        if (isbf) {
            out[w * 20 + lane] = pack_bf2(ax, ay);
        } else {
            float* of = (float*)out;
            of[w * 40 + 2*lane]     = ax;
            of[w * 40 + 2*lane + 1] = ay;
        }
    }
}

extern "C" void kernel_launch(void* const* d_in, const int* in_sizes, int n_in,
                              void* d_out, int out_size, void* d_ws, size_t ws_size,
                              hipStream_t stream) {
    const void* xr = d_in[0];
    const void* xu = d_in[1];
    const void* xp = d_in[2];
    const int*  ei = (const int*)d_in[3];
    const void* Wr = d_in[4];
    const void* br = d_in[5];
    const void* Wu = d_in[6];
    const void* bu = d_in[7];
    const void* Wp = d_in[8];
    const void* bp = d_in[9];
    const void* W1 = d_in[10];
    const void* W2 = d_in[11];
    (void)in_sizes; (void)n_in; (void)out_size; (void)ws_size;

    char* ws = (char*)d_ws;
    size_t off = 0;
    auto alloc = [&](size_t bytes) -> void* {
        void* p = (void*)(ws + off);
        off = (off + bytes + 255) & ~(size_t)255;
        return p;
    };
    int*            flags  = (int*)           alloc(256);
    int*            cmat   = (int*)           alloc((size_t)kCH * kNBp * 4);  // 1.6 MB
    int*            reloff = (int*)           alloc((size_t)kNB * 256 * 4);   // 1.6 MB
    int*            btot   = (int*)           alloc((size_t)kNB * 4);
    int*            bbase  = (int*)           alloc((size_t)(kNB + 1) * 4);
    int*            rp     = (int*)           alloc((size_t)(kN + 1) * 4);
    unsigned short* fwfrag = (unsigned short*)alloc(8 * 64 * 8 * 2);          // 8 KB
    unsigned short* w2frag = (unsigned short*)alloc(12 * 64 * 8 * 2);         // 12 KB
    uint4*          xpack  = (uint4*)         alloc((size_t)kN * 16);         // 1.6 MB
    unsigned int*   pairs  = (unsigned int*)  alloc((size_t)kE * 4);          // 6.4 MB
    int*            col    = (int*)           alloc((size_t)kE * 4);          // 6.4 MB
    unsigned short* hwb    = (unsigned short*)alloc((size_t)kN * kC * 2);     // 8 MB

    gcn_sniff<<<1, 64, 0, stream>>>((const unsigned int*)W1, ei, flags);
    gcn_setup<<<393, 256, 0, stream>>>(xr, xu, xp, Wr, br, Wu, bu, Wp, bp, W1, W2,
                                       fwfrag, w2frag, xpack, flags);
    gcn_count<<<kCH, 512, 0, stream>>>(ei, cmat, flags);
    gcn_scanB1<<<kNB, 256, 0, stream>>>(cmat, reloff, btot);
    gcn_scanB2<<<1, 512, 0, stream>>>(btot, bbase);
    gcn_scatter<<<kCH / kSG, 1024, 0, stream>>>(ei, bbase, reloff, pairs, flags);
    GCN_2190433321521_kernel<<<kNB, 256, 0, stream>>>(pairs, bbase, xpack, fwfrag, w2frag,
                                                      rp, col, hwb, flags);
    gcn_gather2<<<(kN * 64 + 255) / 256, 256, 0, stream>>>((const unsigned int*)hwb, rp, col,
                                                           (unsigned int*)d_out, flags);
}

// Round 16
// 233.430 us; speedup vs baseline: 1.4344x; 1.0414x over previous
//
#include <hip/hip_runtime.h>

constexpr int kNR = 40000;
constexpr int kNU = 30000;
constexpr int kNP = 30000;
constexpr int kN  = 100000;          // total nodes
constexpr int kE  = 1600000;         // edges
constexpr int kF  = 128;             // feature/hidden dim
constexpr int kC  = 40;              // classes
constexpr int kBN = 64;              // nodes per bucket
constexpr int kNB = (kN + kBN - 1) / kBN;   // 1563 buckets
constexpr int kNBp = 1600;           // padded bucket-count stride
constexpr int kCH = 256;             // edge chunks (count/scan granularity)
constexpr int kCE = kE / kCH;        // 6250 edges per chunk
constexpr int kSG = 4;               // chunks per scatter block (64 blocks)
constexpr int kStash = 2048;         // LDS pair-stash capacity (avg bucket 1024)

typedef __attribute__((ext_vector_type(8))) short bf16x8;   // MFMA A/B frag
typedef __attribute__((ext_vector_type(4))) float f32x4;    // MFMA C/D frag

// ---------- bf16 helpers ----------
__device__ __forceinline__ float bf_to_f(unsigned short h) {
    union { unsigned int i; float f; } u; u.i = ((unsigned int)h) << 16; return u.f;
}
__device__ __forceinline__ unsigned short f_to_bf(float f) {
    union { unsigned int i; float f; } u; u.f = f;
    unsigned int r = u.i + 0x7FFFu + ((u.i >> 16) & 1u);   // RNE
    return (unsigned short)(r >> 16);
}
__device__ __forceinline__ float2 bf2_to_f2(unsigned int p) {
    union { unsigned int i; float f; } lo, hi;
    lo.i = (p & 0xFFFFu) << 16;
    hi.i = p & 0xFFFF0000u;
    return make_float2(lo.f, hi.f);
}
__device__ __forceinline__ unsigned int pack_bf2(float a, float b) {
    return (unsigned int)f_to_bf(a) | ((unsigned int)f_to_bf(b) << 16);
}
__device__ __forceinline__ float ldf(const void* p, int i, int isbf) {
    return isbf ? bf_to_f(((const unsigned short*)p)[i]) : ((const float*)p)[i];
}
__device__ __forceinline__ int lde(const int* p, int i, int is64) {
    return is64 ? p[2 * i] : p[i];
}

// ---------- sniff dtypes -> flags[0]=isbf, flags[1]=is64 ----------
__global__ void gcn_sniff(const unsigned int* __restrict__ w1w,
                          const int* __restrict__ eiw, int* __restrict__ flags) {
    if (blockIdx.x != 0 || threadIdx.x != 0) return;
    int plaus = 0;
    for (int k = 0; k < 64; k++) {
        unsigned int ax = w1w[k] & 0x7FFFu;
        plaus += (ax == 0u) || (ax > 0x2000u && ax < 0x4000u);
    }
    flags[0] = (plaus >= 48) ? 1 : 0;
    int nz = 0;
    for (int k = 0; k < 64; k++) nz |= eiw[2 * k + 1];
    flags[1] = (nz == 0) ? 1 : 0;
}

// ---------- setup: pack features + frag-order weight tables (verified R14) ----------
__global__ void __launch_bounds__(256) gcn_setup(
        const void* __restrict__ xr, const void* __restrict__ xu, const void* __restrict__ xp,
        const void* __restrict__ Wr, const void* __restrict__ br,
        const void* __restrict__ Wu, const void* __restrict__ bu,
        const void* __restrict__ Wp, const void* __restrict__ bp,
        const void* __restrict__ W1, const void* __restrict__ W2,
        unsigned short* __restrict__ fwfrag, unsigned short* __restrict__ w2frag,
        uint4* __restrict__ xpack, const int* __restrict__ flags) {
    int isbf = flags[0];
    int t = threadIdx.x;
    if (blockIdx.x == 391) {                 // ---- fuse -> fwfrag ----
        __shared__ float sw[21 * kF];
        __shared__ unsigned short flds[kF * 32];
        for (int i = t; i < 21 * kF; i += 256) {
            int r = i >> 7, c = i & 127;
            float v;
            if (r < 5)        v = ldf(Wr, r * kF + c, isbf);
            else if (r < 12)  v = ldf(Wu, (r - 5) * kF + c, isbf);
            else if (r < 18)  v = ldf(Wp, (r - 12) * kF + c, isbf);
            else if (r == 18) v = ldf(br, c, isbf);
            else if (r == 19) v = ldf(bu, c, isbf);
            else              v = ldf(bp, c, isbf);
            sw[i] = v;
        }
        __syncthreads();
        if (t < 128) {
            int j = t;
            float acc[21];
            #pragma unroll
            for (int r = 0; r < 21; r++) acc[r] = 0.f;
            for (int k = 0; k < kF; k++) {
                float w1 = ldf(W1, k * kF + j, isbf);
                #pragma unroll
                for (int r = 0; r < 21; r++) acc[r] += sw[r * kF + k] * w1;
            }
            unsigned short row[32];
            #pragma unroll
            for (int s = 0; s < 32; s++) row[s] = 0;
            #pragma unroll
            for (int i = 0; i < 5; i++) row[0  + i] = f_to_bf(acc[i]);
            #pragma unroll
            for (int i = 0; i < 7; i++) row[8  + i] = f_to_bf(acc[5 + i]);
            #pragma unroll
            for (int i = 0; i < 6; i++) row[16 + i] = f_to_bf(acc[12 + i]);
            row[24] = f_to_bf(acc[18]);  row[25] = f_to_bf(acc[19]);  row[26] = f_to_bf(acc[20]);
            #pragma unroll
            for (int s = 0; s < 32; s++) flds[j * 32 + s] = row[s];
        }
        __syncthreads();
        for (int idx = t; idx < 8 * 64; idx += 256) {
            int t8 = idx >> 6, lane = idx & 63;
            int mm = lane & 15, q = lane >> 4;
            #pragma unroll
            for (int j = 0; j < 8; j++)
                fwfrag[idx * 8 + j] = flds[(16 * t8 + mm) * 32 + q * 8 + j];
        }
    } else if (blockIdx.x == 392) {          // ---- W2 -> w2frag ----
        for (int idx = t; idx < 12 * 64; idx += 256) {
            int st = idx >> 6, lane = idx & 63;
            int s = st / 3, tt = st % 3;
            int mm = lane & 15, q = lane >> 4;
            int cls = 16 * tt + mm;
            #pragma unroll
            for (int j = 0; j < 8; j++) {
                int k = s * 32 + q * 8 + j;
                w2frag[idx * 8 + j] = (cls < kC) ? f_to_bf(ldf(W2, k * kC + cls, isbf))
                                                 : (unsigned short)0;
            }
        }
    } else {                                 // ---- pack ----
        int n = blockIdx.x * 256 + t;
        if (n >= kN) return;
        const void* base; int roff, d;
        if (n < kNR)            { base = xr; roff = n * 5;               d = 5; }
        else if (n < kNR + kNU) { base = xu; roff = (n - kNR) * 7;       d = 7; }
        else                    { base = xp; roff = (n - kNR - kNU) * 6; d = 6; }
        float f[8];
        #pragma unroll
        for (int i = 0; i < 8; i++) f[i] = (i < d) ? ldf(base, roff + i, isbf) : 0.f;
        uint4 u;
        u.x = pack_bf2(f[0], f[1]);  u.y = pack_bf2(f[2], f[3]);
        u.z = pack_bf2(f[4], f[5]);  u.w = pack_bf2(f[6], f[7]);
        xpack[n] = u;
    }
}

// ---------- multisplit pass 1: per-chunk bucket counts ----------
__global__ void __launch_bounds__(512) gcn_count(const int* __restrict__ ei,
                                                 int* __restrict__ cmat,
                                                 const int* __restrict__ flags) {
    __shared__ int cl[kNBp];
    int is64 = flags[1];
    int blk = blockIdx.x, t = threadIdx.x;
    for (int i = t; i < kNBp; i += 512) cl[i] = 0;
    __syncthreads();
    int e0 = blk * kCE, e1 = e0 + kCE;
    for (int eb = e0 + t; eb < e1; eb += 2048) {
        unsigned int d[4]; int ok[4];
        #pragma unroll
        for (int j = 0; j < 4; j++) {
            int e = eb + j * 512;
            ok[j] = (e < e1);
            d[j] = ok[j] ? (unsigned int)lde(ei, kE + e, is64) : 0u;
        }
        #pragma unroll
        for (int j = 0; j < 4; j++)
            if (ok[j] && d[j] < (unsigned int)kN) atomicAdd(&cl[d[j] >> 6], 1);
    }
    __syncthreads();
    for (int i = t; i < kNBp; i += 512) cmat[blk * kNBp + i] = cl[i];
}

// ---------- pass 2a: per-bucket scan over chunks ----------
__global__ void gcn_scanB1(const int* __restrict__ cmat, int* __restrict__ reloff,
                           int* __restrict__ btot) {
    __shared__ int lds[256];
    int b = blockIdx.x, t = threadIdx.x;
    int v = cmat[t * kNBp + b];
    int incl = v; lds[t] = incl; __syncthreads();
    for (int o = 1; o < 256; o <<= 1) {
        int y = (t >= o) ? lds[t - o] : 0;
        __syncthreads();
        incl += y; lds[t] = incl;
        __syncthreads();
    }
    reloff[b * 256 + t] = incl - v;
    if (t == 255) btot[b] = incl;
}

// ---------- pass 2b: scan bucket totals -> bbase ----------
__global__ void gcn_scanB2(const int* __restrict__ btot, int* __restrict__ bbase) {
    __shared__ int lds[512];
    int t = threadIdx.x;
    int v[4]; int s = 0;
    #pragma unroll
    for (int j = 0; j < 4; j++) {
        int i = 4 * t + j;
        v[j] = (i < kNB) ? btot[i] : 0;
        s += v[j];
    }
    int incl = s; lds[t] = incl; __syncthreads();
    for (int o = 1; o < 512; o <<= 1) {
        int y = (t >= o) ? lds[t - o] : 0;
        __syncthreads();
        incl += y; lds[t] = incl;
        __syncthreads();
    }
    int excl = incl - s;
    #pragma unroll
    for (int j = 0; j < 4; j++) {
        int i = 4 * t + j;
        if (i < kNB) { bbase[i] = excl; excl += v[j]; }
    }
    if (t == 511) bbase[kNB] = incl;
}

// ---------- pass 3: scatter pairs; 64 blocks x 1024 threads ----------
__global__ void __launch_bounds__(1024) gcn_scatter(const int* __restrict__ ei,
                                                    const int* __restrict__ bbase,
                                                    const int* __restrict__ reloff,
                                                    unsigned int* __restrict__ pairs,
                                                    const int* __restrict__ flags) {
    __shared__ int cur[kNB];
    int is64 = flags[1];
    int blk = blockIdx.x, t = threadIdx.x;
    int c0 = blk * kSG;
    for (int i = t; i < kNB; i += 1024) cur[i] = bbase[i] + reloff[i * 256 + c0];
    __syncthreads();
    int e0 = c0 * kCE, e1 = e0 + kSG * kCE;
    for (int eb = e0 + t; eb < e1; eb += 4096) {
        unsigned int d[4], s[4]; int ok[4];
        #pragma unroll
        for (int j = 0; j < 4; j++) {
            int e = eb + j * 1024;
            ok[j] = (e < e1);
            d[j] = ok[j] ? (unsigned int)lde(ei, kE + e, is64) : 0xFFFFFFFFu;
        }
        #pragma unroll
        for (int j = 0; j < 4; j++) {
            int e = eb + j * 1024;
            s[j] = ok[j] ? (unsigned int)lde(ei, e, is64) : 0u;
        }
        #pragma unroll
        for (int j = 0; j < 4; j++) {
            if (d[j] < (unsigned int)kN) {
                unsigned int sv = (s[j] < (unsigned int)kN) ? s[j] : 0u;
                int p = atomicAdd(&cur[d[j] >> 6], 1);
                pairs[p] = (sv << 6) | (d[j] & 63u);
            }
        }
    }
}

// ---------- MEGA bucket kernel: CSR build + layer-1 agg (register acc) + MFMA dense ----------
__global__ void __launch_bounds__(256) GCN_2190433321521_kernel(
        const unsigned int* __restrict__ pairs,
        const int* __restrict__ bbase,
        const uint4* __restrict__ xpack,
        const unsigned short* __restrict__ fwfrag,
        const unsigned short* __restrict__ w2frag,
        int* __restrict__ rp,
        int* __restrict__ col,
        unsigned short* __restrict__ hw,
        const int* __restrict__ flags) {
    __shared__ __align__(16) char smem[25600];
    float*          agg_l  = (float*)smem;                       // [64][29] fp32, 7424 B
    int*            cnt_l  = (int*)(smem + 7424);                // [64] working cursors
    int*            strt_l = (int*)(smem + 7680);                // [64] start cursors
    int*            cntv_l = (int*)(smem + 7936);                // [64] node counts
    unsigned int*   wst    = (unsigned int*)(smem + 8192);       // pair stash [2048], 8 KB
    int*            col_l  = (int*)(smem + 16384);               // col staging [2048], 8 KB
    unsigned short* hbuf   = (unsigned short*)(smem + 8192);     // [4][16][136] (aliases wst+col_l)

    int b = blockIdx.x;
    int base = b * kBN;
    int nn = min(kBN, kN - base);
    int tid = threadIdx.x;
    (void)flags;

    if (tid < kBN) cnt_l[tid] = 0;
    __syncthreads();
    int p0 = bbase[b], p1 = bbase[b + 1];
    int m = p1 - p0;
    bool fits = (m <= kStash);

    // pass 1: load pairs once -> stash + per-node histogram
    for (int ib = p0 + tid; ib < p1; ib += 1024) {
        unsigned int w[4]; int ok[4];
        #pragma unroll
        for (int j = 0; j < 4; j++) {
            int i = ib + j * 256;
            ok[j] = (i < p1);
            w[j] = ok[j] ? pairs[i] : 0u;
        }
        #pragma unroll
        for (int j = 0; j < 4; j++) {
            int i = ib + j * 256;
            if (ok[j]) {
                if (fits) wst[i - p0] = w[j];
                atomicAdd(&cnt_l[w[j] & 63u], 1);
            }
        }
    }
    __syncthreads();
    // wave-0 shfl scan over the 64 node-counts (no barriers inside)
    if (tid < 64) {
        int v = cnt_l[tid];
        int incl = v;
        #pragma unroll
        for (int o = 1; o < 64; o <<= 1) {
            int y = __shfl_up(incl, o, 64);
            if (tid >= o) incl += y;
        }
        int cursor = p0 + incl - v;
        cnt_l[tid]  = cursor;
        strt_l[tid] = cursor;
        cntv_l[tid] = v;
        if (tid < nn) rp[base + tid] = cursor;
        if (b == kNB - 1 && tid == 0) rp[kN] = p1;
    }
    __syncthreads();

    // pass 2a: col build only (1 LDS atomic per edge)
    for (int i = p0 + tid; i < p1; i += 256) {
        unsigned int w = fits ? wst[i - p0] : pairs[i];
        unsigned int s = w >> 6;
        int dloc = (int)(w & 63u);
        int pos = atomicAdd(&cnt_l[dloc], 1);
        if (fits) col_l[pos - p0] = (int)s;
        else      col[pos] = (int)s;
    }
    __syncthreads();
    if (fits) {
        for (int i = tid; i < m; i += 256) col[p0 + i] = col_l[i];
    }

    // pass 2b: 4 threads per node; register accumulation of 27 slots
    {
        int node = tid >> 2, j = tid & 3;
        float aR[8], aU[8], aP[8];
        #pragma unroll
        for (int i = 0; i < 8; i++) { aR[i] = 0.f; aU[i] = 0.f; aP[i] = 0.f; }
        float cR = 0.f, cU = 0.f, cP = 0.f;
        int start = strt_l[node] - p0;
        int c = cntv_l[node];
        for (int i = start + j; i < start + c; i += 4) {
            int s = fits ? col_l[i] : col[p0 + i];
            uint4 u = xpack[s];
            float2 q0 = bf2_to_f2(u.x), q1 = bf2_to_f2(u.y);
            float2 q2 = bf2_to_f2(u.z), q3 = bf2_to_f2(u.w);
            if (s < kNR) {
                aR[0]+=q0.x; aR[1]+=q0.y; aR[2]+=q1.x; aR[3]+=q1.y;
                aR[4]+=q2.x; aR[5]+=q2.y; aR[6]+=q3.x; aR[7]+=q3.y; cR += 1.f;
            } else if (s < kNR + kNU) {
                aU[0]+=q0.x; aU[1]+=q0.y; aU[2]+=q1.x; aU[3]+=q1.y;
                aU[4]+=q2.x; aU[5]+=q2.y; aU[6]+=q3.x; aU[7]+=q3.y; cU += 1.f;
            } else {
                aP[0]+=q0.x; aP[1]+=q0.y; aP[2]+=q1.x; aP[3]+=q1.y;
                aP[4]+=q2.x; aP[5]+=q2.y; aP[6]+=q3.x; aP[7]+=q3.y; cP += 1.f;
            }
        }
        #pragma unroll
        for (int i = 0; i < 8; i++) {
            float v = aR[i];
            v += __shfl_xor(v, 1, 64);  v += __shfl_xor(v, 2, 64);
            if (j == 0) agg_l[node * 29 + i] = v;
        }
        #pragma unroll
        for (int i = 0; i < 8; i++) {
            float v = aU[i];
            v += __shfl_xor(v, 1, 64);  v += __shfl_xor(v, 2, 64);
            if (j == 0) agg_l[node * 29 + 8 + i] = v;
        }
        #pragma unroll
        for (int i = 0; i < 8; i++) {
            float v = aP[i];
            v += __shfl_xor(v, 1, 64);  v += __shfl_xor(v, 2, 64);
            if (j == 0) agg_l[node * 29 + 16 + i] = v;
        }
        float v = cR;
        v += __shfl_xor(v, 1, 64);  v += __shfl_xor(v, 2, 64);
        if (j == 0) agg_l[node * 29 + 24] = v;
        v = cU;
        v += __shfl_xor(v, 1, 64);  v += __shfl_xor(v, 2, 64);
        if (j == 0) agg_l[node * 29 + 25] = v;
        v = cP;
        v += __shfl_xor(v, 1, 64);  v += __shfl_xor(v, 2, 64);
        if (j == 0) agg_l[node * 29 + 26] = v;
    }
    __syncthreads();   // agg_l complete; wst/col_l dead -> hbuf region live

    // ---- fused dense (MFMA): each wave = one 16-node tile; B-frags from global ----
    int wid = tid >> 6, lane = tid & 63;
    int mm = lane & 15, q = lane >> 4;
    int node = wid * 16 + mm;
    bf16x8 a1;
    #pragma unroll
    for (int j = 0; j < 8; j++) {
        int sl = q * 8 + j;
        a1[j] = (sl < 27) ? (short)f_to_bf(agg_l[node * 29 + sl]) : (short)0;
    }
    const bf16x8* fwf = (const bf16x8*)fwfrag;
    f32x4 c1[8];
    #pragma unroll
    for (int t = 0; t < 8; t++) {
        f32x4 z = {0.f, 0.f, 0.f, 0.f};
        c1[t] = __builtin_amdgcn_mfma_f32_16x16x32_bf16(a1, fwf[t * 64 + lane], z, 0, 0, 0);
    }
    unsigned short* hb = hbuf + wid * 16 * 136;
    #pragma unroll
    for (int t = 0; t < 8; t++) {
        #pragma unroll
        for (int r = 0; r < 4; r++)
            hb[(q * 4 + r) * 136 + 16 * t + mm] = f_to_bf(fmaxf(c1[t][r], 0.f));
    }
    const bf16x8* w2f = (const bf16x8*)w2frag;
    f32x4 c2[3];
    #pragma unroll
    for (int t = 0; t < 3; t++) { c2[t].x = 0.f; c2[t].y = 0.f; c2[t].z = 0.f; c2[t].w = 0.f; }
    #pragma unroll
    for (int s = 0; s < 4; s++) {
        bf16x8 a2 = *(const bf16x8*)&hb[mm * 136 + s * 32 + q * 8];
        #pragma unroll
        for (int t = 0; t < 3; t++)
            c2[t] = __builtin_amdgcn_mfma_f32_16x16x32_bf16(a2, w2f[(s * 3 + t) * 64 + lane],
                                                            c2[t], 0, 0, 0);
    }
    #pragma unroll
    for (int t = 0; t < 3; t++) {
        int cls = 16 * t + mm;
        if (cls < kC) {
            #pragma unroll
            for (int r = 0; r < 4; r++) {
                int n = base + wid * 16 + q * 4 + r;
                if (n < kN) hw[(size_t)n * kC + cls] = f_to_bf(c2[t][r]);
            }
        }
    }
}

// ---------- layer-2 gather: wave-per-node, 6 groups x 10 lanes x dwordx2 ----------
// Halves vector-mem requests/edge (20 dword -> 10 dwordx2); 6 edges in flight/wave;
// avg per-group chain ~2.7 gathers (was ~5.3).
__global__ void __launch_bounds__(256) gcn_gather2(const unsigned int* __restrict__ hw32,
                                                   const int* __restrict__ rp,
                                                   const int* __restrict__ col,
                                                   unsigned int* __restrict__ out,
                                                   const int* __restrict__ flags) {
    int isbf = flags[0];
    int w = (blockIdx.x * 256 + threadIdx.x) >> 6;
    if (w >= kN) return;
    int lane = threadIdx.x & 63;
    int grp = lane / 10;          // 0..5 active, 6 (lanes 60-63) idle
    int c2  = lane % 10;          // dword-pair index: classes 4*c2 .. 4*c2+3
    int beg = rp[w], end = rp[w + 1];
    float f0 = 0.f, f1 = 0.f, f2 = 0.f, f3 = 0.f;
    if (grp < 6) {
        const uint2* hp = (const uint2*)hw32;
        int e = beg + grp;
        for (; e + 6 < end; e += 12) {             // 2 edges in flight per group
            int s0 = col[e], s1 = col[e + 6];
            uint2 v0 = hp[s0 * 10 + c2];
            uint2 v1 = hp[s1 * 10 + c2];
            float2 a0 = bf2_to_f2(v0.x), b0 = bf2_to_f2(v0.y);
            float2 a1 = bf2_to_f2(v1.x), b1 = bf2_to_f2(v1.y);
            f0 += a0.x + a1.x;  f1 += a0.y + a1.y;
            f2 += b0.x + b1.x;  f3 += b0.y + b1.y;
        }
        if (e < end) {
            uint2 v = hp[col[e] * 10 + c2];
            float2 a = bf2_to_f2(v.x), bb = bf2_to_f2(v.y);
            f0 += a.x; f1 += a.y; f2 += bb.x; f3 += bb.y;
        }
    }
    // fold groups 3..5 onto 0..2, then 1..2 onto 0 (lanes 0..9 end correct)
    f0 += __shfl(f0, lane + 30, 64);
    f1 += __shfl(f1, lane + 30, 64);
    f2 += __shfl(f2, lane + 30, 64);
    f3 += __shfl(f3, lane + 30, 64);
    f0 += __shfl(f0, lane + 10, 64) + __shfl(f0, lane + 20, 64);
    f1 += __shfl(f1, lane + 10, 64) + __shfl(f1, lane + 20, 64);
    f2 += __shfl(f2, lane + 10, 64) + __shfl(f2, lane + 20, 64);
    f3 += __shfl(f3, lane + 10, 64) + __shfl(f3, lane + 20, 64);
    if (lane < 10) {
        if (isbf) {
            out[w * 20 + 2 * lane]     = pack_bf2(f0, f1);
            out[w * 20 + 2 * lane + 1] = pack_bf2(f2, f3);
        } else {
            float* of = (float*)out;
            of[w * 40 + 4 * lane]     = f0;
            of[w * 40 + 4 * lane + 1] = f1;
            of[w * 40 + 4 * lane + 2] = f2;
            of[w * 40 + 4 * lane + 3] = f3;
        }
    }
}

extern "C" void kernel_launch(void* const* d_in, const int* in_sizes, int n_in,
                              void* d_out, int out_size, void* d_ws, size_t ws_size,
                              hipStream_t stream) {
    const void* xr = d_in[0];
    const void* xu = d_in[1];
    const void* xp = d_in[2];
    const int*  ei = (const int*)d_in[3];
    const void* Wr = d_in[4];
    const void* br = d_in[5];
    const void* Wu = d_in[6];
    const void* bu = d_in[7];
    const void* Wp = d_in[8];
    const void* bp = d_in[9];
    const void* W1 = d_in[10];
    const void* W2 = d_in[11];
    (void)in_sizes; (void)n_in; (void)out_size; (void)ws_size;

    char* ws = (char*)d_ws;
    size_t off = 0;
    auto alloc = [&](size_t bytes) -> void* {
        void* p = (void*)(ws + off);
        off = (off + bytes + 255) & ~(size_t)255;
        return p;
    };
    int*            flags  = (int*)           alloc(256);
    int*            cmat   = (int*)           alloc((size_t)kCH * kNBp * 4);  // 1.6 MB
    int*            reloff = (int*)           alloc((size_t)kNB * 256 * 4);   // 1.6 MB
    int*            btot   = (int*)           alloc((size_t)kNB * 4);
    int*            bbase  = (int*)           alloc((size_t)(kNB + 1) * 4);
    int*            rp     = (int*)           alloc((size_t)(kN + 1) * 4);
    unsigned short* fwfrag = (unsigned short*)alloc(8 * 64 * 8 * 2);          // 8 KB
    unsigned short* w2frag = (unsigned short*)alloc(12 * 64 * 8 * 2);         // 12 KB
    uint4*          xpack  = (uint4*)         alloc((size_t)kN * 16);         // 1.6 MB
    unsigned int*   pairs  = (unsigned int*)  alloc((size_t)kE * 4);          // 6.4 MB
    int*            col    = (int*)           alloc((size_t)kE * 4);          // 6.4 MB
    unsigned short* hwb    = (unsigned short*)alloc((size_t)kN * kC * 2);     // 8 MB

    gcn_sniff<<<1, 64, 0, stream>>>((const unsigned int*)W1, ei, flags);
    gcn_setup<<<393, 256, 0, stream>>>(xr, xu, xp, Wr, br, Wu, bu, Wp, bp, W1, W2,
                                       fwfrag, w2frag, xpack, flags);
    gcn_count<<<kCH, 512, 0, stream>>>(ei, cmat, flags);
    gcn_scanB1<<<kNB, 256, 0, stream>>>(cmat, reloff, btot);
    gcn_scanB2<<<1, 512, 0, stream>>>(btot, bbase);
    gcn_scatter<<<kCH / kSG, 1024, 0, stream>>>(ei, bbase, reloff, pairs, flags);
    GCN_2190433321521_kernel<<<kNB, 256, 0, stream>>>(pairs, bbase, xpack, fwfrag, w2frag,
                                                      rp, col, hwb, flags);
    gcn_gather2<<<(kN * 64 + 255) / 256, 256, 0, stream>>>((const unsigned int*)hwb, rp, col,
                                                           (unsigned int*)d_out, flags);
}

// Round 17
// 206.322 us; speedup vs baseline: 1.6228x; 1.1314x over previous
//
#include <hip/hip_runtime.h>

constexpr int kNR = 40000;
constexpr int kNU = 30000;
constexpr int kNP = 30000;
constexpr int kN  = 100000;          // total nodes
constexpr int kE  = 1600000;         // edges
constexpr int kF  = 128;             // feature/hidden dim
constexpr int kC  = 40;              // classes
constexpr int kBN = 64;              // nodes per bucket
constexpr int kNB = (kN + kBN - 1) / kBN;   // 1563 buckets
constexpr int kNBp = 1600;           // padded bucket-count stride
constexpr int kCH = 256;             // edge chunks (count/scan granularity)
constexpr int kCE = kE / kCH;        // 6250 edges per chunk
constexpr int kSG = 2;               // chunks per scatter block (128 blocks)
constexpr int kStash = 2048;         // LDS pair-stash capacity (avg bucket 1024)

typedef __attribute__((ext_vector_type(8))) short bf16x8;   // MFMA A/B frag
typedef __attribute__((ext_vector_type(4))) float f32x4;    // MFMA C/D frag

// ---------- bf16 helpers ----------
__device__ __forceinline__ float bf_to_f(unsigned short h) {
    union { unsigned int i; float f; } u; u.i = ((unsigned int)h) << 16; return u.f;
}
__device__ __forceinline__ unsigned short f_to_bf(float f) {
    union { unsigned int i; float f; } u; u.f = f;
    unsigned int r = u.i + 0x7FFFu + ((u.i >> 16) & 1u);   // RNE
    return (unsigned short)(r >> 16);
}
__device__ __forceinline__ float2 bf2_to_f2(unsigned int p) {
    union { unsigned int i; float f; } lo, hi;
    lo.i = (p & 0xFFFFu) << 16;
    hi.i = p & 0xFFFF0000u;
    return make_float2(lo.f, hi.f);
}
__device__ __forceinline__ unsigned int pack_bf2(float a, float b) {
    return (unsigned int)f_to_bf(a) | ((unsigned int)f_to_bf(b) << 16);
}
__device__ __forceinline__ float ldf(const void* p, int i, int isbf) {
    return isbf ? bf_to_f(((const unsigned short*)p)[i]) : ((const float*)p)[i];
}
__device__ __forceinline__ int lde(const int* p, int i, int is64) {
    return is64 ? p[2 * i] : p[i];
}

// ---------- sniff dtypes -> flags[0]=isbf, flags[1]=is64 ----------
__global__ void gcn_sniff(const unsigned int* __restrict__ w1w,
                          const int* __restrict__ eiw, int* __restrict__ flags) {
    if (blockIdx.x != 0 || threadIdx.x != 0) return;
    int plaus = 0;
    for (int k = 0; k < 64; k++) {
        unsigned int ax = w1w[k] & 0x7FFFu;
        plaus += (ax == 0u) || (ax > 0x2000u && ax < 0x4000u);
    }
    flags[0] = (plaus >= 48) ? 1 : 0;
    int nz = 0;
    for (int k = 0; k < 64; k++) nz |= eiw[2 * k + 1];
    flags[1] = (nz == 0) ? 1 : 0;
}

// ---------- setup: pack features + frag-order weight tables ----------
// Fuse block now split-k: 2 threads per column (halves the serial chain).
__global__ void __launch_bounds__(256) gcn_setup(
        const void* __restrict__ xr, const void* __restrict__ xu, const void* __restrict__ xp,
        const void* __restrict__ Wr, const void* __restrict__ br,
        const void* __restrict__ Wu, const void* __restrict__ bu,
        const void* __restrict__ Wp, const void* __restrict__ bp,
        const void* __restrict__ W1, const void* __restrict__ W2,
        unsigned short* __restrict__ fwfrag, unsigned short* __restrict__ w2frag,
        uint4* __restrict__ xpack, const int* __restrict__ flags) {
    int isbf = flags[0];
    int t = threadIdx.x;
    if (blockIdx.x == 391) {                 // ---- fuse -> fwfrag (split-k over 256 thr) ----
        __shared__ float sw[21 * kF];              // 10.5 KB
        __shared__ float pacc[21 * kF];            // 10.5 KB: half-1 partials
        __shared__ unsigned short flds[kF * 32];   // 8 KB
        for (int i = t; i < 21 * kF; i += 256) {
            int r = i >> 7, c = i & 127;
            float v;
            if (r < 5)        v = ldf(Wr, r * kF + c, isbf);
            else if (r < 12)  v = ldf(Wu, (r - 5) * kF + c, isbf);
            else if (r < 18)  v = ldf(Wp, (r - 12) * kF + c, isbf);
            else if (r == 18) v = ldf(br, c, isbf);
            else if (r == 19) v = ldf(bu, c, isbf);
            else              v = ldf(bp, c, isbf);
            sw[i] = v;
        }
        __syncthreads();
        {
            int j = t & 127, half = t >> 7;        // column, k-half
            int k0 = half * 64, k1 = k0 + 64;
            float acc[21];
            #pragma unroll
            for (int r = 0; r < 21; r++) acc[r] = 0.f;
            for (int k = k0; k < k1; k++) {
                float w1 = ldf(W1, k * kF + j, isbf);
                #pragma unroll
                for (int r = 0; r < 21; r++) acc[r] += sw[r * kF + k] * w1;
            }
            if (half == 1) {
                #pragma unroll
                for (int r = 0; r < 21; r++) pacc[r * kF + j] = acc[r];
            }
            __syncthreads();
            if (half == 0) {
                #pragma unroll
                for (int r = 0; r < 21; r++) acc[r] += pacc[r * kF + j];
                unsigned short row[32];
                #pragma unroll
                for (int s = 0; s < 32; s++) row[s] = 0;
                #pragma unroll
                for (int i = 0; i < 5; i++) row[0  + i] = f_to_bf(acc[i]);
                #pragma unroll
                for (int i = 0; i < 7; i++) row[8  + i] = f_to_bf(acc[5 + i]);
                #pragma unroll
                for (int i = 0; i < 6; i++) row[16 + i] = f_to_bf(acc[12 + i]);
                row[24] = f_to_bf(acc[18]);  row[25] = f_to_bf(acc[19]);  row[26] = f_to_bf(acc[20]);
                #pragma unroll
                for (int s = 0; s < 32; s++) flds[j * 32 + s] = row[s];
            }
        }
        __syncthreads();
        for (int idx = t; idx < 8 * 64; idx += 256) {
            int t8 = idx >> 6, lane = idx & 63;
            int mm = lane & 15, q = lane >> 4;
            #pragma unroll
            for (int j = 0; j < 8; j++)
                fwfrag[idx * 8 + j] = flds[(16 * t8 + mm) * 32 + q * 8 + j];
        }
    } else if (blockIdx.x == 392) {          // ---- W2 -> w2frag ----
        for (int idx = t; idx < 12 * 64; idx += 256) {
            int st = idx >> 6, lane = idx & 63;
            int s = st / 3, tt = st % 3;
            int mm = lane & 15, q = lane >> 4;
            int cls = 16 * tt + mm;
            #pragma unroll
            for (int j = 0; j < 8; j++) {
                int k = s * 32 + q * 8 + j;
                w2frag[idx * 8 + j] = (cls < kC) ? f_to_bf(ldf(W2, k * kC + cls, isbf))
                                                 : (unsigned short)0;
            }
        }
    } else {                                 // ---- pack ----
        int n = blockIdx.x * 256 + t;
        if (n >= kN) return;
        const void* base; int roff, d;
        if (n < kNR)            { base = xr; roff = n * 5;               d = 5; }
        else if (n < kNR + kNU) { base = xu; roff = (n - kNR) * 7;       d = 7; }
        else                    { base = xp; roff = (n - kNR - kNU) * 6; d = 6; }
        float f[8];
        #pragma unroll
        for (int i = 0; i < 8; i++) f[i] = (i < d) ? ldf(base, roff + i, isbf) : 0.f;
        uint4 u;
        u.x = pack_bf2(f[0], f[1]);  u.y = pack_bf2(f[2], f[3]);
        u.z = pack_bf2(f[4], f[5]);  u.w = pack_bf2(f[6], f[7]);
        xpack[n] = u;
    }
}

// ---------- multisplit pass 1: per-chunk bucket counts ----------
__global__ void __launch_bounds__(512) gcn_count(const int* __restrict__ ei,
                                                 int* __restrict__ cmat,
                                                 const int* __restrict__ flags) {
    __shared__ int cl[kNBp];
    int is64 = flags[1];
    int blk = blockIdx.x, t = threadIdx.x;
    for (int i = t; i < kNBp; i += 512) cl[i] = 0;
    __syncthreads();
    int e0 = blk * kCE, e1 = e0 + kCE;
    for (int eb = e0 + t; eb < e1; eb += 2048) {
        unsigned int d[4]; int ok[4];
        #pragma unroll
        for (int j = 0; j < 4; j++) {
            int e = eb + j * 512;
            ok[j] = (e < e1);
            d[j] = ok[j] ? (unsigned int)lde(ei, kE + e, is64) : 0u;
        }
        #pragma unroll
        for (int j = 0; j < 4; j++)
            if (ok[j] && d[j] < (unsigned int)kN) atomicAdd(&cl[d[j] >> 6], 1);
    }
    __syncthreads();
    for (int i = t; i < kNBp; i += 512) cmat[blk * kNBp + i] = cl[i];
}

// ---------- pass 2a: per-bucket scan over chunks ----------
__global__ void gcn_scanB1(const int* __restrict__ cmat, int* __restrict__ reloff,
                           int* __restrict__ btot) {
    __shared__ int lds[256];
    int b = blockIdx.x, t = threadIdx.x;
    int v = cmat[t * kNBp + b];
    int incl = v; lds[t] = incl; __syncthreads();
    for (int o = 1; o < 256; o <<= 1) {
        int y = (t >= o) ? lds[t - o] : 0;
        __syncthreads();
        incl += y; lds[t] = incl;
        __syncthreads();
    }
    reloff[b * 256 + t] = incl - v;
    if (t == 255) btot[b] = incl;
}

// ---------- pass 2b: scan bucket totals -> bbase ----------
__global__ void gcn_scanB2(const int* __restrict__ btot, int* __restrict__ bbase) {
    __shared__ int lds[512];
    int t = threadIdx.x;
    int v[4]; int s = 0;
    #pragma unroll
    for (int j = 0; j < 4; j++) {
        int i = 4 * t + j;
        v[j] = (i < kNB) ? btot[i] : 0;
        s += v[j];
    }
    int incl = s; lds[t] = incl; __syncthreads();
    for (int o = 1; o < 512; o <<= 1) {
        int y = (t >= o) ? lds[t - o] : 0;
        __syncthreads();
        incl += y; lds[t] = incl;
        __syncthreads();
    }
    int excl = incl - s;
    #pragma unroll
    for (int j = 0; j < 4; j++) {
        int i = 4 * t + j;
        if (i < kNB) { bbase[i] = excl; excl += v[j]; }
    }
    if (t == 511) bbase[kNB] = incl;
}

// ---------- pass 3: scatter pairs; 128 blocks x 2 consecutive chunks ----------
// Runs per (block,bucket) ~8 edges = 32B: 2 blocks/line (bounded 2x amp) but 2x CU
// coverage vs R16's 64 blocks (scatter was 45.8us at 6% occupancy).
__global__ void __launch_bounds__(1024) gcn_scatter(const int* __restrict__ ei,
                                                    const int* __restrict__ bbase,
                                                    const int* __restrict__ reloff,
                                                    unsigned int* __restrict__ pairs,
                                                    const int* __restrict__ flags) {
    __shared__ int cur[kNB];
    int is64 = flags[1];
    int blk = blockIdx.x, t = threadIdx.x;
    int c0 = blk * kSG;
    for (int i = t; i < kNB; i += 1024) cur[i] = bbase[i] + reloff[i * 256 + c0];
    __syncthreads();
    int e0 = c0 * kCE, e1 = e0 + kSG * kCE;
    for (int eb = e0 + t; eb < e1; eb += 4096) {
        unsigned int d[4], s[4]; int ok[4];
        #pragma unroll
        for (int j = 0; j < 4; j++) {
            int e = eb + j * 1024;
            ok[j] = (e < e1);
            d[j] = ok[j] ? (unsigned int)lde(ei, kE + e, is64) : 0xFFFFFFFFu;
        }
        #pragma unroll
        for (int j = 0; j < 4; j++) {
            int e = eb + j * 1024;
            s[j] = ok[j] ? (unsigned int)lde(ei, e, is64) : 0u;
        }
        #pragma unroll
        for (int j = 0; j < 4; j++) {
            if (d[j] < (unsigned int)kN) {
                unsigned int sv = (s[j] < (unsigned int)kN) ? s[j] : 0u;
                int p = atomicAdd(&cur[d[j] >> 6], 1);
                pairs[p] = (sv << 6) | (d[j] & 63u);
            }
        }
    }
}

// ---------- MEGA bucket kernel: CSR build + layer-1 agg (register acc) + MFMA dense ----------
__global__ void __launch_bounds__(256) GCN_2190433321521_kernel(
        const unsigned int* __restrict__ pairs,
        const int* __restrict__ bbase,
        const uint4* __restrict__ xpack,
        const unsigned short* __restrict__ fwfrag,
        const unsigned short* __restrict__ w2frag,
        int* __restrict__ rp,
        int* __restrict__ col,
        unsigned short* __restrict__ hw,
        const int* __restrict__ flags) {
    __shared__ __align__(16) char smem[25600];
    float*          agg_l  = (float*)smem;                       // [64][29] fp32, 7424 B
    int*            cnt_l  = (int*)(smem + 7424);                // [64] working cursors
    int*            strt_l = (int*)(smem + 7680);                // [64] start cursors
    int*            cntv_l = (int*)(smem + 7936);                // [64] node counts
    unsigned int*   wst    = (unsigned int*)(smem + 8192);       // pair stash [2048], 8 KB
    int*            col_l  = (int*)(smem + 16384);               // col staging [2048], 8 KB
    unsigned short* hbuf   = (unsigned short*)(smem + 8192);     // [4][16][136] (aliases wst+col_l)

    int b = blockIdx.x;
    int base = b * kBN;
    int nn = min(kBN, kN - base);
    int tid = threadIdx.x;
    (void)flags;

    if (tid < kBN) cnt_l[tid] = 0;
    __syncthreads();
    int p0 = bbase[b], p1 = bbase[b + 1];
    int m = p1 - p0;
    bool fits = (m <= kStash);

    // pass 1: load pairs once -> stash + per-node histogram
    for (int ib = p0 + tid; ib < p1; ib += 1024) {
        unsigned int w[4]; int ok[4];
        #pragma unroll
        for (int j = 0; j < 4; j++) {
            int i = ib + j * 256;
            ok[j] = (i < p1);
            w[j] = ok[j] ? pairs[i] : 0u;
        }
        #pragma unroll
        for (int j = 0; j < 4; j++) {
            int i = ib + j * 256;
            if (ok[j]) {
                if (fits) wst[i - p0] = w[j];
                atomicAdd(&cnt_l[w[j] & 63u], 1);
            }
        }
    }
    __syncthreads();
    // wave-0 shfl scan over the 64 node-counts
    if (tid < 64) {
        int v = cnt_l[tid];
        int incl = v;
        #pragma unroll
        for (int o = 1; o < 64; o <<= 1) {
            int y = __shfl_up(incl, o, 64);
            if (tid >= o) incl += y;
        }
        int cursor = p0 + incl - v;
        cnt_l[tid]  = cursor;
        strt_l[tid] = cursor;
        cntv_l[tid] = v;
        if (tid < nn) rp[base + tid] = cursor;
        if (b == kNB - 1 && tid == 0) rp[kN] = p1;
    }
    __syncthreads();

    // pass 2a: col build only (1 LDS atomic per edge)
    for (int i = p0 + tid; i < p1; i += 256) {
        unsigned int w = fits ? wst[i - p0] : pairs[i];
        unsigned int s = w >> 6;
        int dloc = (int)(w & 63u);
        int pos = atomicAdd(&cnt_l[dloc], 1);
        if (fits) col_l[pos - p0] = (int)s;
        else      col[pos] = (int)s;
    }
    __syncthreads();
    if (fits) {
        for (int i = tid; i < m; i += 256) col[p0 + i] = col_l[i];
    }

    // pass 2b: 4 threads per node; register accumulation of 27 slots
    {
        int node = tid >> 2, j = tid & 3;
        float aR[8], aU[8], aP[8];
        #pragma unroll
        for (int i = 0; i < 8; i++) { aR[i] = 0.f; aU[i] = 0.f; aP[i] = 0.f; }
        float cR = 0.f, cU = 0.f, cP = 0.f;
        int start = strt_l[node] - p0;
        int c = cntv_l[node];
        for (int i = start + j; i < start + c; i += 4) {
            int s = fits ? col_l[i] : col[p0 + i];
            uint4 u = xpack[s];
            float2 q0 = bf2_to_f2(u.x), q1 = bf2_to_f2(u.y);
            float2 q2 = bf2_to_f2(u.z), q3 = bf2_to_f2(u.w);
            if (s < kNR) {
                aR[0]+=q0.x; aR[1]+=q0.y; aR[2]+=q1.x; aR[3]+=q1.y;
                aR[4]+=q2.x; aR[5]+=q2.y; aR[6]+=q3.x; aR[7]+=q3.y; cR += 1.f;
            } else if (s < kNR + kNU) {
                aU[0]+=q0.x; aU[1]+=q0.y; aU[2]+=q1.x; aU[3]+=q1.y;
                aU[4]+=q2.x; aU[5]+=q2.y; aU[6]+=q3.x; aU[7]+=q3.y; cU += 1.f;
            } else {
                aP[0]+=q0.x; aP[1]+=q0.y; aP[2]+=q1.x; aP[3]+=q1.y;
                aP[4]+=q2.x; aP[5]+=q2.y; aP[6]+=q3.x; aP[7]+=q3.y; cP += 1.f;
            }
        }
        #pragma unroll
        for (int i = 0; i < 8; i++) {
            float v = aR[i];
            v += __shfl_xor(v, 1, 64);  v += __shfl_xor(v, 2, 64);
            if (j == 0) agg_l[node * 29 + i] = v;
        }
        #pragma unroll
        for (int i = 0; i < 8; i++) {
            float v = aU[i];
            v += __shfl_xor(v, 1, 64);  v += __shfl_xor(v, 2, 64);
            if (j == 0) agg_l[node * 29 + 8 + i] = v;
        }
        #pragma unroll
        for (int i = 0; i < 8; i++) {
            float v = aP[i];
            v += __shfl_xor(v, 1, 64);  v += __shfl_xor(v, 2, 64);
            if (j == 0) agg_l[node * 29 + 16 + i] = v;
        }
        float v = cR;
        v += __shfl_xor(v, 1, 64);  v += __shfl_xor(v, 2, 64);
        if (j == 0) agg_l[node * 29 + 24] = v;
        v = cU;
        v += __shfl_xor(v, 1, 64);  v += __shfl_xor(v, 2, 64);
        if (j == 0) agg_l[node * 29 + 25] = v;
        v = cP;
        v += __shfl_xor(v, 1, 64);  v += __shfl_xor(v, 2, 64);
        if (j == 0) agg_l[node * 29 + 26] = v;
    }
    __syncthreads();   // agg_l complete; wst/col_l dead -> hbuf region live

    // ---- fused dense (MFMA): each wave = one 16-node tile; B-frags from global ----
    int wid = tid >> 6, lane = tid & 63;
    int mm = lane & 15, q = lane >> 4;
    int node = wid * 16 + mm;
    bf16x8 a1;
    #pragma unroll
    for (int j = 0; j < 8; j++) {
        int sl = q * 8 + j;
        a1[j] = (sl < 27) ? (short)f_to_bf(agg_l[node * 29 + sl]) : (short)0;
    }
    const bf16x8* fwf = (const bf16x8*)fwfrag;
    f32x4 c1[8];
    #pragma unroll
    for (int t = 0; t < 8; t++) {
        f32x4 z = {0.f, 0.f, 0.f, 0.f};
        c1[t] = __builtin_amdgcn_mfma_f32_16x16x32_bf16(a1, fwf[t * 64 + lane], z, 0, 0, 0);
    }
    unsigned short* hb = hbuf + wid * 16 * 136;
    #pragma unroll
    for (int t = 0; t < 8; t++) {
        #pragma unroll
        for (int r = 0; r < 4; r++)
            hb[(q * 4 + r) * 136 + 16 * t + mm] = f_to_bf(fmaxf(c1[t][r], 0.f));
    }
    const bf16x8* w2f = (const bf16x8*)w2frag;
    f32x4 c2[3];
    #pragma unroll
    for (int t = 0; t < 3; t++) { c2[t].x = 0.f; c2[t].y = 0.f; c2[t].z = 0.f; c2[t].w = 0.f; }
    #pragma unroll
    for (int s = 0; s < 4; s++) {
        bf16x8 a2 = *(const bf16x8*)&hb[mm * 136 + s * 32 + q * 8];
        #pragma unroll
        for (int t = 0; t < 3; t++)
            c2[t] = __builtin_amdgcn_mfma_f32_16x16x32_bf16(a2, w2f[(s * 3 + t) * 64 + lane],
                                                            c2[t], 0, 0, 0);
    }
    #pragma unroll
    for (int t = 0; t < 3; t++) {
        int cls = 16 * t + mm;
        if (cls < kC) {
            #pragma unroll
            for (int r = 0; r < 4; r++) {
                int n = base + wid * 16 + q * 4 + r;
                if (n < kN) hw[(size_t)n * kC + cls] = f_to_bf(c2[t][r]);
            }
        }
    }
}

// ---------- layer-2 gather: wave-per-node, 6 groups x 10 lanes x dwordx2 ----------
__global__ void __launch_bounds__(256) gcn_gather2(const unsigned int* __restrict__ hw32,
                                                   const int* __restrict__ rp,
                                                   const int* __restrict__ col,
                                                   unsigned int* __restrict__ out,
                                                   const int* __restrict__ flags) {
    int isbf = flags[0];
    int w = (blockIdx.x * 256 + threadIdx.x) >> 6;
    if (w >= kN) return;
    int lane = threadIdx.x & 63;
    int grp = lane / 10;          // 0..5 active, 6 (lanes 60-63) idle
    int c2  = lane % 10;          // dword-pair index: classes 4*c2 .. 4*c2+3
    int beg = rp[w], end = rp[w + 1];
    float f0 = 0.f, f1 = 0.f, f2 = 0.f, f3 = 0.f;
    if (grp < 6) {
        const uint2* hp = (const uint2*)hw32;
        int e = beg + grp;
        for (; e + 6 < end; e += 12) {             // 2 edges in flight per group
            int s0 = col[e], s1 = col[e + 6];
            uint2 v0 = hp[s0 * 10 + c2];
            uint2 v1 = hp[s1 * 10 + c2];
            float2 a0 = bf2_to_f2(v0.x), b0 = bf2_to_f2(v0.y);
            float2 a1 = bf2_to_f2(v1.x), b1 = bf2_to_f2(v1.y);
            f0 += a0.x + a1.x;  f1 += a0.y + a1.y;
            f2 += b0.x + b1.x;  f3 += b0.y + b1.y;
        }
        if (e < end) {
            uint2 v = hp[col[e] * 10 + c2];
            float2 a = bf2_to_f2(v.x), bb = bf2_to_f2(v.y);
            f0 += a.x; f1 += a.y; f2 += bb.x; f3 += bb.y;
        }
    }
    f0 += __shfl(f0, lane + 30, 64);
    f1 += __shfl(f1, lane + 30, 64);
    f2 += __shfl(f2, lane + 30, 64);
    f3 += __shfl(f3, lane + 30, 64);
    f0 += __shfl(f0, lane + 10, 64) + __shfl(f0, lane + 20, 64);
    f1 += __shfl(f1, lane + 10, 64) + __shfl(f1, lane + 20, 64);
    f2 += __shfl(f2, lane + 10, 64) + __shfl(f2, lane + 20, 64);
    f3 += __shfl(f3, lane + 10, 64) + __shfl(f3, lane + 20, 64);
    if (lane < 10) {
        if (isbf) {
            out[w * 20 + 2 * lane]     = pack_bf2(f0, f1);
            out[w * 20 + 2 * lane + 1] = pack_bf2(f2, f3);
        } else {
            float* of = (float*)out;
            of[w * 40 + 4 * lane]     = f0;
            of[w * 40 + 4 * lane + 1] = f1;
            of[w * 40 + 4 * lane + 2] = f2;
            of[w * 40 + 4 * lane + 3] = f3;
        }
    }
}

extern "C" void kernel_launch(void* const* d_in, const int* in_sizes, int n_in,
                              void* d_out, int out_size, void* d_ws, size_t ws_size,
                              hipStream_t stream) {
    const void* xr = d_in[0];
    const void* xu = d_in[1];
    const void* xp = d_in[2];
    const int*  ei = (const int*)d_in[3];
    const void* Wr = d_in[4];
    const void* br = d_in[5];
    const void* Wu = d_in[6];
    const void* bu = d_in[7];
    const void* Wp = d_in[8];
    const void* bp = d_in[9];
    const void* W1 = d_in[10];
    const void* W2 = d_in[11];
    (void)in_sizes; (void)n_in; (void)out_size; (void)ws_size;

    char* ws = (char*)d_ws;
    size_t off = 0;
    auto alloc = [&](size_t bytes) -> void* {
        void* p = (void*)(ws + off);
        off = (off + bytes + 255) & ~(size_t)255;
        return p;
    };
    int*            flags  = (int*)           alloc(256);
    int*            cmat   = (int*)           alloc((size_t)kCH * kNBp * 4);  // 1.6 MB
    int*            reloff = (int*)           alloc((size_t)kNB * 256 * 4);   // 1.6 MB
    int*            btot   = (int*)           alloc((size_t)kNB * 4);
    int*            bbase  = (int*)           alloc((size_t)(kNB + 1) * 4);
    int*            rp     = (int*)           alloc((size_t)(kN + 1) * 4);
    unsigned short* fwfrag = (unsigned short*)alloc(8 * 64 * 8 * 2);          // 8 KB
    unsigned short* w2frag = (unsigned short*)alloc(12 * 64 * 8 * 2);         // 12 KB
    uint4*          xpack  = (uint4*)         alloc((size_t)kN * 16);         // 1.6 MB
    unsigned int*   pairs  = (unsigned int*)  alloc((size_t)kE * 4);          // 6.4 MB
    int*            col    = (int*)           alloc((size_t)kE * 4);          // 6.4 MB
    unsigned short* hwb    = (unsigned short*)alloc((size_t)kN * kC * 2);     // 8 MB

    gcn_sniff<<<1, 64, 0, stream>>>((const unsigned int*)W1, ei, flags);
    gcn_setup<<<393, 256, 0, stream>>>(xr, xu, xp, Wr, br, Wu, bu, Wp, bp, W1, W2,
                                       fwfrag, w2frag, xpack, flags);
    gcn_count<<<kCH, 512, 0, stream>>>(ei, cmat, flags);
    gcn_scanB1<<<kNB, 256, 0, stream>>>(cmat, reloff, btot);
    gcn_scanB2<<<1, 512, 0, stream>>>(btot, bbase);
    gcn_scatter<<<kCH / kSG, 1024, 0, stream>>>(ei, bbase, reloff, pairs, flags);
    GCN_2190433321521_kernel<<<kNB, 256, 0, stream>>>(pairs, bbase, xpack, fwfrag, w2frag,
                                                      rp, col, hwb, flags);
    gcn_gather2<<<(kN * 64 + 255) / 256, 256, 0, stream>>>((const unsigned int*)hwb, rp, col,
                                                           (unsigned int*)d_out, flags);
}

// Round 18
// 200.117 us; speedup vs baseline: 1.6732x; 1.0310x over previous
//
#include <hip/hip_runtime.h>

constexpr int kNR = 40000;
constexpr int kNU = 30000;
constexpr int kNP = 30000;
constexpr int kN  = 100000;          // total nodes
constexpr int kE  = 1600000;         // edges
constexpr int kF  = 128;             // feature/hidden dim
constexpr int kC  = 40;              // classes
constexpr int kBN = 64;              // nodes per bucket
constexpr int kNB = (kN + kBN - 1) / kBN;   // 1563 buckets
constexpr int kNBp = 1600;           // padded bucket-count stride
constexpr int kCH = 256;             // edge chunks (count/scan granularity)
constexpr int kCE = kE / kCH;        // 6250 edges per chunk
constexpr int kSG = 1;               // chunks per scatter block (256 blocks)
constexpr int kStash = 2048;         // LDS pair-stash capacity (avg bucket 1024)
constexpr int kPackB = 196;          // pack blocks (512 thr): 196*512 >= kN
constexpr int kSetupB = kPackB + 2 + kCH;   // 454 blocks total

typedef __attribute__((ext_vector_type(8))) short bf16x8;   // MFMA A/B frag
typedef __attribute__((ext_vector_type(4))) float f32x4;    // MFMA C/D frag

// ---------- bf16 helpers ----------
__device__ __forceinline__ float bf_to_f(unsigned short h) {
    union { unsigned int i; float f; } u; u.i = ((unsigned int)h) << 16; return u.f;
}
__device__ __forceinline__ unsigned short f_to_bf(float f) {
    union { unsigned int i; float f; } u; u.f = f;
    unsigned int r = u.i + 0x7FFFu + ((u.i >> 16) & 1u);   // RNE
    return (unsigned short)(r >> 16);
}
__device__ __forceinline__ float2 bf2_to_f2(unsigned int p) {
    union { unsigned int i; float f; } lo, hi;
    lo.i = (p & 0xFFFFu) << 16;
    hi.i = p & 0xFFFF0000u;
    return make_float2(lo.f, hi.f);
}
__device__ __forceinline__ unsigned int pack_bf2(float a, float b) {
    return (unsigned int)f_to_bf(a) | ((unsigned int)f_to_bf(b) << 16);
}
__device__ __forceinline__ float ldf(const void* p, int i, int isbf) {
    return isbf ? bf_to_f(((const unsigned short*)p)[i]) : ((const float*)p)[i];
}
__device__ __forceinline__ int lde(const int* p, int i, int is64) {
    return is64 ? p[2 * i] : p[i];
}

// ---------- sniff dtypes -> flags[0]=isbf, flags[1]=is64 ----------
__global__ void gcn_sniff(const unsigned int* __restrict__ w1w,
                          const int* __restrict__ eiw, int* __restrict__ flags) {
    if (blockIdx.x != 0 || threadIdx.x != 0) return;
    int plaus = 0;
    for (int k = 0; k < 64; k++) {
        unsigned int ax = w1w[k] & 0x7FFFu;
        plaus += (ax == 0u) || (ax > 0x2000u && ax < 0x4000u);
    }
    flags[0] = (plaus >= 48) ? 1 : 0;
    int nz = 0;
    for (int k = 0; k < 64; k++) nz |= eiw[2 * k + 1];
    flags[1] = (nz == 0) ? 1 : 0;
}

// ---------- MERGED setup+count: blocks 0..195 pack | 196 fuse | 197 w2frag | 198..453 count ----------
// setup and count are independent -> run concurrently in one dispatch (saves ~25us serial).
__global__ void __launch_bounds__(512) gcn_setup(
        const void* __restrict__ xr, const void* __restrict__ xu, const void* __restrict__ xp,
        const void* __restrict__ Wr, const void* __restrict__ br,
        const void* __restrict__ Wu, const void* __restrict__ bu,
        const void* __restrict__ Wp, const void* __restrict__ bp,
        const void* __restrict__ W1, const void* __restrict__ W2,
        const int* __restrict__ ei,
        unsigned short* __restrict__ fwfrag, unsigned short* __restrict__ w2frag,
        uint4* __restrict__ xpack, int* __restrict__ cmat,
        const int* __restrict__ flags) {
    __shared__ __align__(16) char smem[29696];
    int isbf = flags[0];
    int t = threadIdx.x;
    int bx = blockIdx.x;
    if (bx < kPackB) {                       // ---- pack (512 thr) ----
        int n = bx * 512 + t;
        if (n >= kN) return;
        const void* base; int roff, d;
        if (n < kNR)            { base = xr; roff = n * 5;               d = 5; }
        else if (n < kNR + kNU) { base = xu; roff = (n - kNR) * 7;       d = 7; }
        else                    { base = xp; roff = (n - kNR - kNU) * 6; d = 6; }
        float f[8];
        #pragma unroll
        for (int i = 0; i < 8; i++) f[i] = (i < d) ? ldf(base, roff + i, isbf) : 0.f;
        uint4 u;
        u.x = pack_bf2(f[0], f[1]);  u.y = pack_bf2(f[2], f[3]);
        u.z = pack_bf2(f[4], f[5]);  u.w = pack_bf2(f[6], f[7]);
        xpack[n] = u;
    } else if (bx == kPackB) {               // ---- fuse -> fwfrag (split-k, 256 active) ----
        float* sw   = (float*)smem;                          // 21*128 f32 = 10752 B
        float* pacc = (float*)(smem + 10752);                // 10752 B
        unsigned short* flds = (unsigned short*)(smem + 21504);  // 8192 B
        for (int i = t; i < 21 * kF; i += 512) {
            int r = i >> 7, c = i & 127;
            float v;
            if (r < 5)        v = ldf(Wr, r * kF + c, isbf);
            else if (r < 12)  v = ldf(Wu, (r - 5) * kF + c, isbf);
            else if (r < 18)  v = ldf(Wp, (r - 12) * kF + c, isbf);
            else if (r == 18) v = ldf(br, c, isbf);
            else if (r == 19) v = ldf(bu, c, isbf);
            else              v = ldf(bp, c, isbf);
            sw[i] = v;
        }
        __syncthreads();
        {
            bool active = (t < 256);
            int j = t & 127, half = (t >> 7) & 1;
            float acc[21];
            #pragma unroll
            for (int r = 0; r < 21; r++) acc[r] = 0.f;
            if (active) {
                int k0 = half * 64, k1 = k0 + 64;
                for (int k = k0; k < k1; k++) {
                    float w1 = ldf(W1, k * kF + j, isbf);
                    #pragma unroll
                    for (int r = 0; r < 21; r++) acc[r] += sw[r * kF + k] * w1;
                }
            }
            if (active && half == 1) {
                #pragma unroll
                for (int r = 0; r < 21; r++) pacc[r * kF + j] = acc[r];
            }
            __syncthreads();
            if (active && half == 0) {
                #pragma unroll
                for (int r = 0; r < 21; r++) acc[r] += pacc[r * kF + j];
                unsigned short row[32];
                #pragma unroll
                for (int s = 0; s < 32; s++) row[s] = 0;
                #pragma unroll
                for (int i = 0; i < 5; i++) row[0  + i] = f_to_bf(acc[i]);
                #pragma unroll
                for (int i = 0; i < 7; i++) row[8  + i] = f_to_bf(acc[5 + i]);
                #pragma unroll
                for (int i = 0; i < 6; i++) row[16 + i] = f_to_bf(acc[12 + i]);
                row[24] = f_to_bf(acc[18]);  row[25] = f_to_bf(acc[19]);  row[26] = f_to_bf(acc[20]);
                #pragma unroll
                for (int s = 0; s < 32; s++) flds[j * 32 + s] = row[s];
            }
        }
        __syncthreads();
        for (int idx = t; idx < 8 * 64; idx += 512) {
            int t8 = idx >> 6, lane = idx & 63;
            int mm = lane & 15, q = lane >> 4;
            #pragma unroll
            for (int j = 0; j < 8; j++)
                fwfrag[idx * 8 + j] = flds[(16 * t8 + mm) * 32 + q * 8 + j];
        }
    } else if (bx == kPackB + 1) {           // ---- W2 -> w2frag ----
        for (int idx = t; idx < 12 * 64; idx += 512) {
            int st = idx >> 6, lane = idx & 63;
            int s = st / 3, tt = st % 3;
            int mm = lane & 15, q = lane >> 4;
            int cls = 16 * tt + mm;
            #pragma unroll
            for (int j = 0; j < 8; j++) {
                int k = s * 32 + q * 8 + j;
                w2frag[idx * 8 + j] = (cls < kC) ? f_to_bf(ldf(W2, k * kC + cls, isbf))
                                                 : (unsigned short)0;
            }
        }
    } else {                                 // ---- count (chunk = bx - kPackB - 2) ----
        int* cl = (int*)smem;                // 1600 ints = 6400 B
        int is64 = flags[1];
        int blk = bx - kPackB - 2;
        for (int i = t; i < kNBp; i += 512) cl[i] = 0;
        __syncthreads();
        int e0 = blk * kCE, e1 = e0 + kCE;
        for (int eb = e0 + t; eb < e1; eb += 2048) {
            unsigned int d[4]; int ok[4];
            #pragma unroll
            for (int j = 0; j < 4; j++) {
                int e = eb + j * 512;
                ok[j] = (e < e1);
                d[j] = ok[j] ? (unsigned int)lde(ei, kE + e, is64) : 0u;
            }
            #pragma unroll
            for (int j = 0; j < 4; j++)
                if (ok[j] && d[j] < (unsigned int)kN) atomicAdd(&cl[d[j] >> 6], 1);
        }
        __syncthreads();
        for (int i = t; i < kNBp; i += 512) cmat[blk * kNBp + i] = cl[i];
    }
}

// ---------- pass 2a: per-bucket scan over chunks ----------
__global__ void gcn_scanB1(const int* __restrict__ cmat, int* __restrict__ reloff,
                           int* __restrict__ btot) {
    __shared__ int lds[256];
    int b = blockIdx.x, t = threadIdx.x;
    int v = cmat[t * kNBp + b];
    int incl = v; lds[t] = incl; __syncthreads();
    for (int o = 1; o < 256; o <<= 1) {
        int y = (t >= o) ? lds[t - o] : 0;
        __syncthreads();
        incl += y; lds[t] = incl;
        __syncthreads();
    }
    reloff[b * 256 + t] = incl - v;
    if (t == 255) btot[b] = incl;
}

// ---------- pass 2b: scan bucket totals -> bbase ----------
__global__ void gcn_scanB2(const int* __restrict__ btot, int* __restrict__ bbase) {
    __shared__ int lds[512];
    int t = threadIdx.x;
    int v[4]; int s = 0;
    #pragma unroll
    for (int j = 0; j < 4; j++) {
        int i = 4 * t + j;
        v[j] = (i < kNB) ? btot[i] : 0;
        s += v[j];
    }
    int incl = s; lds[t] = incl; __syncthreads();
    for (int o = 1; o < 512; o <<= 1) {
        int y = (t >= o) ? lds[t - o] : 0;
        __syncthreads();
        incl += y; lds[t] = incl;
        __syncthreads();
    }
    int excl = incl - s;
    #pragma unroll
    for (int j = 0; j < 4; j++) {
        int i = 4 * t + j;
        if (i < kNB) { bbase[i] = excl; excl += v[j]; }
    }
    if (t == 511) bbase[kNB] = incl;
}

// ---------- pass 3: scatter pairs; 256 blocks x 1 chunk (full CU coverage) ----------
__global__ void __launch_bounds__(1024) gcn_scatter(const int* __restrict__ ei,
                                                    const int* __restrict__ bbase,
                                                    const int* __restrict__ reloff,
                                                    unsigned int* __restrict__ pairs,
                                                    const int* __restrict__ flags) {
    __shared__ int cur[kNB];
    int is64 = flags[1];
    int blk = blockIdx.x, t = threadIdx.x;
    int c0 = blk * kSG;
    for (int i = t; i < kNB; i += 1024) cur[i] = bbase[i] + reloff[i * 256 + c0];
    __syncthreads();
    int e0 = c0 * kCE, e1 = e0 + kSG * kCE;
    for (int eb = e0 + t; eb < e1; eb += 4096) {
        unsigned int d[4], s[4]; int ok[4];
        #pragma unroll
        for (int j = 0; j < 4; j++) {
            int e = eb + j * 1024;
            ok[j] = (e < e1);
            d[j] = ok[j] ? (unsigned int)lde(ei, kE + e, is64) : 0xFFFFFFFFu;
        }
        #pragma unroll
        for (int j = 0; j < 4; j++) {
            int e = eb + j * 1024;
            s[j] = ok[j] ? (unsigned int)lde(ei, e, is64) : 0u;
        }
        #pragma unroll
        for (int j = 0; j < 4; j++) {
            if (d[j] < (unsigned int)kN) {
                unsigned int sv = (s[j] < (unsigned int)kN) ? s[j] : 0u;
                int p = atomicAdd(&cur[d[j] >> 6], 1);
                pairs[p] = (sv << 6) | (d[j] & 63u);
            }
        }
    }
}

// ---------- MEGA bucket kernel: CSR build + layer-1 agg (register acc) + MFMA dense ----------
__global__ void __launch_bounds__(256) GCN_2190433321521_kernel(
        const unsigned int* __restrict__ pairs,
        const int* __restrict__ bbase,
        const uint4* __restrict__ xpack,
        const unsigned short* __restrict__ fwfrag,
        const unsigned short* __restrict__ w2frag,
        int* __restrict__ rp,
        int* __restrict__ col,
        unsigned short* __restrict__ hw,
        const int* __restrict__ flags) {
    __shared__ __align__(16) char smem[25600];
    float*          agg_l  = (float*)smem;                       // [64][29] fp32, 7424 B
    int*            cnt_l  = (int*)(smem + 7424);                // [64] working cursors
    int*            strt_l = (int*)(smem + 7680);                // [64] start cursors
    int*            cntv_l = (int*)(smem + 7936);                // [64] node counts
    unsigned int*   wst    = (unsigned int*)(smem + 8192);       // pair stash [2048], 8 KB
    int*            col_l  = (int*)(smem + 16384);               // col staging [2048], 8 KB
    unsigned short* hbuf   = (unsigned short*)(smem + 8192);     // [4][16][136] (aliases wst+col_l)

    int b = blockIdx.x;
    int base = b * kBN;
    int nn = min(kBN, kN - base);
    int tid = threadIdx.x;
    (void)flags;

    if (tid < kBN) cnt_l[tid] = 0;
    __syncthreads();
    int p0 = bbase[b], p1 = bbase[b + 1];
    int m = p1 - p0;
    bool fits = (m <= kStash);

    // pass 1: load pairs once -> stash + per-node histogram
    for (int ib = p0 + tid; ib < p1; ib += 1024) {
        unsigned int w[4]; int ok[4];
        #pragma unroll
        for (int j = 0; j < 4; j++) {
            int i = ib + j * 256;
            ok[j] = (i < p1);
            w[j] = ok[j] ? pairs[i] : 0u;
        }
        #pragma unroll
        for (int j = 0; j < 4; j++) {
            int i = ib + j * 256;
            if (ok[j]) {
                if (fits) wst[i - p0] = w[j];
                atomicAdd(&cnt_l[w[j] & 63u], 1);
            }
        }
    }
    __syncthreads();
    // wave-0 shfl scan over the 64 node-counts
    if (tid < 64) {
        int v = cnt_l[tid];
        int incl = v;
        #pragma unroll
        for (int o = 1; o < 64; o <<= 1) {
            int y = __shfl_up(incl, o, 64);
            if (tid >= o) incl += y;
        }
        int cursor = p0 + incl - v;
        cnt_l[tid]  = cursor;
        strt_l[tid] = cursor;
        cntv_l[tid] = v;
        if (tid < nn) rp[base + tid] = cursor;
        if (b == kNB - 1 && tid == 0) rp[kN] = p1;
    }
    __syncthreads();

    // pass 2a: col build only (1 LDS atomic per edge)
    for (int i = p0 + tid; i < p1; i += 256) {
        unsigned int w = fits ? wst[i - p0] : pairs[i];
        unsigned int s = w >> 6;
        int dloc = (int)(w & 63u);
        int pos = atomicAdd(&cnt_l[dloc], 1);
        if (fits) col_l[pos - p0] = (int)s;
        else      col[pos] = (int)s;
    }
    __syncthreads();
    if (fits) {
        for (int i = tid; i < m; i += 256) col[p0 + i] = col_l[i];
    }

    // pass 2b: 4 threads per node; register accumulation of 27 slots
    {
        int node = tid >> 2, j = tid & 3;
        float aR[8], aU[8], aP[8];
        #pragma unroll
        for (int i = 0; i < 8; i++) { aR[i] = 0.f; aU[i] = 0.f; aP[i] = 0.f; }
        float cR = 0.f, cU = 0.f, cP = 0.f;
        int start = strt_l[node] - p0;
        int c = cntv_l[node];
        for (int i = start + j; i < start + c; i += 4) {
            int s = fits ? col_l[i] : col[p0 + i];
            uint4 u = xpack[s];
            float2 q0 = bf2_to_f2(u.x), q1 = bf2_to_f2(u.y);
            float2 q2 = bf2_to_f2(u.z), q3 = bf2_to_f2(u.w);
            if (s < kNR) {
                aR[0]+=q0.x; aR[1]+=q0.y; aR[2]+=q1.x; aR[3]+=q1.y;
                aR[4]+=q2.x; aR[5]+=q2.y; aR[6]+=q3.x; aR[7]+=q3.y; cR += 1.f;
            } else if (s < kNR + kNU) {
                aU[0]+=q0.x; aU[1]+=q0.y; aU[2]+=q1.x; aU[3]+=q1.y;
                aU[4]+=q2.x; aU[5]+=q2.y; aU[6]+=q3.x; aU[7]+=q3.y; cU += 1.f;
            } else {
                aP[0]+=q0.x; aP[1]+=q0.y; aP[2]+=q1.x; aP[3]+=q1.y;
                aP[4]+=q2.x; aP[5]+=q2.y; aP[6]+=q3.x; aP[7]+=q3.y; cP += 1.f;
            }
        }
        #pragma unroll
        for (int i = 0; i < 8; i++) {
            float v = aR[i];
            v += __shfl_xor(v, 1, 64);  v += __shfl_xor(v, 2, 64);
            if (j == 0) agg_l[node * 29 + i] = v;
        }
        #pragma unroll
        for (int i = 0; i < 8; i++) {
            float v = aU[i];
            v += __shfl_xor(v, 1, 64);  v += __shfl_xor(v, 2, 64);
            if (j == 0) agg_l[node * 29 + 8 + i] = v;
        }
        #pragma unroll
        for (int i = 0; i < 8; i++) {
            float v = aP[i];
            v += __shfl_xor(v, 1, 64);  v += __shfl_xor(v, 2, 64);
            if (j == 0) agg_l[node * 29 + 16 + i] = v;
        }
        float v = cR;
        v += __shfl_xor(v, 1, 64);  v += __shfl_xor(v, 2, 64);
        if (j == 0) agg_l[node * 29 + 24] = v;
        v = cU;
        v += __shfl_xor(v, 1, 64);  v += __shfl_xor(v, 2, 64);
        if (j == 0) agg_l[node * 29 + 25] = v;
        v = cP;
        v += __shfl_xor(v, 1, 64);  v += __shfl_xor(v, 2, 64);
        if (j == 0) agg_l[node * 29 + 26] = v;
    }
    __syncthreads();   // agg_l complete; wst/col_l dead -> hbuf region live

    // ---- fused dense (MFMA): each wave = one 16-node tile; B-frags from global ----
    int wid = tid >> 6, lane = tid & 63;
    int mm = lane & 15, q = lane >> 4;
    int node = wid * 16 + mm;
    bf16x8 a1;
    #pragma unroll
    for (int j = 0; j < 8; j++) {
        int sl = q * 8 + j;
        a1[j] = (sl < 27) ? (short)f_to_bf(agg_l[node * 29 + sl]) : (short)0;
    }
    const bf16x8* fwf = (const bf16x8*)fwfrag;
    f32x4 c1[8];
    #pragma unroll
    for (int t = 0; t < 8; t++) {
        f32x4 z = {0.f, 0.f, 0.f, 0.f};
        c1[t] = __builtin_amdgcn_mfma_f32_16x16x32_bf16(a1, fwf[t * 64 + lane], z, 0, 0, 0);
    }
    unsigned short* hb = hbuf + wid * 16 * 136;
    #pragma unroll
    for (int t = 0; t < 8; t++) {
        #pragma unroll
        for (int r = 0; r < 4; r++)
            hb[(q * 4 + r) * 136 + 16 * t + mm] = f_to_bf(fmaxf(c1[t][r], 0.f));
    }
    const bf16x8* w2f = (const bf16x8*)w2frag;
    f32x4 c2[3];
    #pragma unroll
    for (int t = 0; t < 3; t++) { c2[t].x = 0.f; c2[t].y = 0.f; c2[t].z = 0.f; c2[t].w = 0.f; }
    #pragma unroll
    for (int s = 0; s < 4; s++) {
        bf16x8 a2 = *(const bf16x8*)&hb[mm * 136 + s * 32 + q * 8];
        #pragma unroll
        for (int t = 0; t < 3; t++)
            c2[t] = __builtin_amdgcn_mfma_f32_16x16x32_bf16(a2, w2f[(s * 3 + t) * 64 + lane],
                                                            c2[t], 0, 0, 0);
    }
    #pragma unroll
    for (int t = 0; t < 3; t++) {
        int cls = 16 * t + mm;
        if (cls < kC) {
            #pragma unroll
            for (int r = 0; r < 4; r++) {
                int n = base + wid * 16 + q * 4 + r;
                if (n < kN) hw[(size_t)n * kC + cls] = f_to_bf(c2[t][r]);
            }
        }
    }
}

// ---------- layer-2 gather: wave-per-node, 6 groups x 10 lanes x dwordx2 ----------
__global__ void __launch_bounds__(256) gcn_gather2(const unsigned int* __restrict__ hw32,
                                                   const int* __restrict__ rp,
                                                   const int* __restrict__ col,
                                                   unsigned int* __restrict__ out,
                                                   const int* __restrict__ flags) {
    int isbf = flags[0];
    int w = (blockIdx.x * 256 + threadIdx.x) >> 6;
    if (w >= kN) return;
    int lane = threadIdx.x & 63;
    int grp = lane / 10;          // 0..5 active, lanes 60-63 idle
    int c2  = lane % 10;          // dword-pair index: classes 4*c2 .. 4*c2+3
    int beg = rp[w], end = rp[w + 1];
    float f0 = 0.f, f1 = 0.f, f2 = 0.f, f3 = 0.f;
    if (grp < 6) {
        const uint2* hp = (const uint2*)hw32;
        int e = beg + grp;
        for (; e + 6 < end; e += 12) {             // 2 edges in flight per group
            int s0 = col[e], s1 = col[e + 6];
            uint2 v0 = hp[s0 * 10 + c2];
            uint2 v1 = hp[s1 * 10 + c2];
            float2 a0 = bf2_to_f2(v0.x), b0 = bf2_to_f2(v0.y);
            float2 a1 = bf2_to_f2(v1.x), b1 = bf2_to_f2(v1.y);
            f0 += a0.x + a1.x;  f1 += a0.y + a1.y;
            f2 += b0.x + b1.x;  f3 += b0.y + b1.y;
        }
        if (e < end) {
            uint2 v = hp[col[e] * 10 + c2];
            float2 a = bf2_to_f2(v.x), bb = bf2_to_f2(v.y);
            f0 += a.x; f1 += a.y; f2 += bb.x; f3 += bb.y;
        }
    }
    f0 += __shfl(f0, lane + 30, 64);
    f1 += __shfl(f1, lane + 30, 64);
    f2 += __shfl(f2, lane + 30, 64);
    f3 += __shfl(f3, lane + 30, 64);
    f0 += __shfl(f0, lane + 10, 64) + __shfl(f0, lane + 20, 64);
    f1 += __shfl(f1, lane + 10, 64) + __shfl(f1, lane + 20, 64);
    f2 += __shfl(f2, lane + 10, 64) + __shfl(f2, lane + 20, 64);
    f3 += __shfl(f3, lane + 10, 64) + __shfl(f3, lane + 20, 64);
    if (lane < 10) {
        if (isbf) {
            out[w * 20 + 2 * lane]     = pack_bf2(f0, f1);
            out[w * 20 + 2 * lane + 1] = pack_bf2(f2, f3);
        } else {
            float* of = (float*)out;
            of[w * 40 + 4 * lane]     = f0;
            of[w * 40 + 4 * lane + 1] = f1;
            of[w * 40 + 4 * lane + 2] = f2;
            of[w * 40 + 4 * lane + 3] = f3;
        }
    }
}

extern "C" void kernel_launch(void* const* d_in, const int* in_sizes, int n_in,
                              void* d_out, int out_size, void* d_ws, size_t ws_size,
                              hipStream_t stream) {
    const void* xr = d_in[0];
    const void* xu = d_in[1];
    const void* xp = d_in[2];
    const int*  ei = (const int*)d_in[3];
    const void* Wr = d_in[4];
    const void* br = d_in[5];
    const void* Wu = d_in[6];
    const void* bu = d_in[7];
    const void* Wp = d_in[8];
    const void* bp = d_in[9];
    const void* W1 = d_in[10];
    const void* W2 = d_in[11];
    (void)in_sizes; (void)n_in; (void)out_size; (void)ws_size;

    char* ws = (char*)d_ws;
    size_t off = 0;
    auto alloc = [&](size_t bytes) -> void* {
        void* p = (void*)(ws + off);
        off = (off + bytes + 255) & ~(size_t)255;
        return p;
    };
    int*            flags  = (int*)           alloc(256);
    int*            cmat   = (int*)           alloc((size_t)kCH * kNBp * 4);  // 1.6 MB
    int*            reloff = (int*)           alloc((size_t)kNB * 256 * 4);   // 1.6 MB
    int*            btot   = (int*)           alloc((size_t)kNB * 4);
    int*            bbase  = (int*)           alloc((size_t)(kNB + 1) * 4);
    int*            rp     = (int*)           alloc((size_t)(kN + 1) * 4);
    unsigned short* fwfrag = (unsigned short*)alloc(8 * 64 * 8 * 2);          // 8 KB
    unsigned short* w2frag = (unsigned short*)alloc(12 * 64 * 8 * 2);         // 12 KB
    uint4*          xpack  = (uint4*)         alloc((size_t)kN * 16);         // 1.6 MB
    unsigned int*   pairs  = (unsigned int*)  alloc((size_t)kE * 4);          // 6.4 MB
    int*            col    = (int*)           alloc((size_t)kE * 4);          // 6.4 MB
    unsigned short* hwb    = (unsigned short*)alloc((size_t)kN * kC * 2);     // 8 MB

    gcn_sniff<<<1, 64, 0, stream>>>((const unsigned int*)W1, ei, flags);
    gcn_setup<<<kSetupB, 512, 0, stream>>>(xr, xu, xp, Wr, br, Wu, bu, Wp, bp, W1, W2,
                                           ei, fwfrag, w2frag, xpack, cmat, flags);
    gcn_scanB1<<<kNB, 256, 0, stream>>>(cmat, reloff, btot);
    gcn_scanB2<<<1, 512, 0, stream>>>(btot, bbase);
    gcn_scatter<<<kCH / kSG, 1024, 0, stream>>>(ei, bbase, reloff, pairs, flags);
    GCN_2190433321521_kernel<<<kNB, 256, 0, stream>>>(pairs, bbase, xpack, fwfrag, w2frag,
                                                      rp, col, hwb, flags);
    gcn_gather2<<<(kN * 64 + 255) / 256, 256, 0, stream>>>((const unsigned int*)hwb, rp, col,
                                                           (unsigned int*)d_out, flags);
}